// Round 1
// baseline (2968.314 us; speedup 1.0000x reference)
//
#include <hip/hip_runtime.h>

#define DIM 128
#define D4 32   // DIM/4

// ---- degree / normalization ----
__global__ void k_deg_init(float* __restrict__ deg, int n) {
    int i = blockIdx.x * blockDim.x + threadIdx.x;
    if (i < n) deg[i] = 1.0f;   // self-loop contributes 1 to every node
}

__global__ void k_deg_count(const int* __restrict__ dst, int E, float* __restrict__ deg) {
    int e = blockIdx.x * blockDim.x + threadIdx.x;
    if (e < E) atomicAdd(&deg[dst[e]], 1.0f);
}

__global__ void k_dinv(float* __restrict__ deg, int n) {
    int i = blockIdx.x * blockDim.x + threadIdx.x;
    if (i < n) deg[i] = rsqrtf(deg[i]);   // deg >= 1 always (self-loop)
}

// ---- aggregation: agg (= d_out) = dinv^2 * x  then += edges ----
__global__ void k_agg_init(const float* __restrict__ x, const float* __restrict__ dinv,
                           float* __restrict__ agg, int n) {
    long t = (long)blockIdx.x * blockDim.x + threadIdx.x;
    long total = (long)n * D4;
    if (t >= total) return;
    int row = (int)(t >> 5);
    int c   = (int)(t & 31);
    float s = dinv[row]; s = s * s;
    float4 v = ((const float4*)x)[(long)row * D4 + c];
    v.x *= s; v.y *= s; v.z *= s; v.w *= s;
    ((float4*)agg)[(long)row * D4 + c] = v;
}

__global__ void k_scatter(const int* __restrict__ ei, const float* __restrict__ x,
                          const float* __restrict__ dinv, float* __restrict__ agg, int E) {
    long t = (long)blockIdx.x * blockDim.x + threadIdx.x;
    long total = (long)E * D4;
    if (t >= total) return;
    int e = (int)(t >> 5);
    int c = (int)(t & 31);
    int s = ei[e];        // src row
    int d = ei[E + e];    // dst row
    float w = dinv[s] * dinv[d];
    float4 v = ((const float4*)x)[(long)s * D4 + c];
    float* o = agg + (long)d * DIM + c * 4;
    atomicAdd(o + 0, w * v.x);
    atomicAdd(o + 1, w * v.y);
    atomicAdd(o + 2, w * v.z);
    atomicAdd(o + 3, w * v.w);
}

// ---- in-place transform: out = dropout(relu(agg @ W + b)) ----
#define RPG 8   // rows per 32-lane group

__global__ __launch_bounds__(256) void k_transform(
        float* __restrict__ io, const float* __restrict__ W,
        const float* __restrict__ bias, const float* __restrict__ du, int n) {
    __shared__ float4 Wl[DIM * D4];   // 64 KB: Wl[k*32 + j4] = W[k][4j4..4j4+3]
    const float4* W4 = (const float4*)W;
    for (int i = threadIdx.x; i < DIM * D4; i += blockDim.x) Wl[i] = W4[i];
    __syncthreads();

    const int l = threadIdx.x & 31;   // output col group (4 cols)
    const int g = threadIdx.x >> 5;   // row group 0..7
    const float4 bb = ((const float4*)bias)[l];
    const float inv_keep = 1.0f / 0.9f;
    const long rows_per_blk = 8 * RPG;   // 64

    for (long base = (long)blockIdx.x * rows_per_blk; base < n;
         base += (long)gridDim.x * rows_per_blk) {
        long r0 = base + (long)g * RPG;
        float4 acc[RPG];
#pragma unroll
        for (int r = 0; r < RPG; ++r) acc[r] = make_float4(0.f, 0.f, 0.f, 0.f);

        for (int k4 = 0; k4 < D4; ++k4) {
            float4 w0 = Wl[(k4 * 4 + 0) * D4 + l];
            float4 w1 = Wl[(k4 * 4 + 1) * D4 + l];
            float4 w2 = Wl[(k4 * 4 + 2) * D4 + l];
            float4 w3 = Wl[(k4 * 4 + 3) * D4 + l];
#pragma unroll
            for (int r = 0; r < RPG; ++r) {
                long row = r0 + r;
                if (row < n) {
                    float4 a = ((const float4*)io)[row * D4 + k4];  // uniform per group
                    acc[r].x += a.x * w0.x + a.y * w1.x + a.z * w2.x + a.w * w3.x;
                    acc[r].y += a.x * w0.y + a.y * w1.y + a.z * w2.y + a.w * w3.y;
                    acc[r].z += a.x * w0.z + a.y * w1.z + a.z * w2.z + a.w * w3.z;
                    acc[r].w += a.x * w0.w + a.y * w1.w + a.z * w2.w + a.w * w3.w;
                }
            }
        }

#pragma unroll
        for (int r = 0; r < RPG; ++r) {
            long row = r0 + r;
            if (row < n) {
                float4 v = acc[r];
                v.x += bb.x; v.y += bb.y; v.z += bb.z; v.w += bb.w;
                float4 u = ((const float4*)du)[row * D4 + l];
                v.x = (u.x >= 0.1f) ? fmaxf(v.x, 0.f) * inv_keep : 0.f;
                v.y = (u.y >= 0.1f) ? fmaxf(v.y, 0.f) * inv_keep : 0.f;
                v.z = (u.z >= 0.1f) ? fmaxf(v.z, 0.f) * inv_keep : 0.f;
                v.w = (u.w >= 0.1f) ? fmaxf(v.w, 0.f) * inv_keep : 0.f;
                ((float4*)io)[row * D4 + l] = v;
            }
        }
    }
}

extern "C" void kernel_launch(void* const* d_in, const int* in_sizes, int n_in,
                              void* d_out, int out_size, void* d_ws, size_t ws_size,
                              hipStream_t stream) {
    const float* x  = (const float*)d_in[0];
    const int*   ei = (const int*)d_in[1];    // [2,E] int32: row0=src, row1=dst
    const float* W  = (const float*)d_in[2];
    const float* b  = (const float*)d_in[3];
    const float* du = (const float*)d_in[4];
    float* out = (float*)d_out;

    const int n = in_sizes[0] / DIM;
    const int E = in_sizes[1] / 2;
    float* deg = (float*)d_ws;   // N floats, overwritten fully each call

    const int bs = 256;
    k_deg_init<<<(n + bs - 1) / bs, bs, 0, stream>>>(deg, n);
    k_deg_count<<<(E + bs - 1) / bs, bs, 0, stream>>>(ei + E, E, deg);
    k_dinv<<<(n + bs - 1) / bs, bs, 0, stream>>>(deg, n);

    long t_agg = (long)n * D4;
    k_agg_init<<<(int)((t_agg + bs - 1) / bs), bs, 0, stream>>>(x, deg, out, n);

    long t_sc = (long)E * D4;
    k_scatter<<<(int)((t_sc + bs - 1) / bs), bs, 0, stream>>>(ei, x, deg, out, E);

    int blocks_t = (int)((n + 63) / 64);
    k_transform<<<blocks_t, 256, 0, stream>>>(out, W, b, du, n);
}

// Round 2
// 516.167 us; speedup vs baseline: 5.7507x; 5.7507x over previous
//
#include <hip/hip_runtime.h>

#define DIM 128
#define D4 32    // DIM/4
#define D2 64    // DIM/2

// ---------- histogram of dst (int) ----------
__global__ void k_hist(const int* __restrict__ dst, int E, int* __restrict__ hist) {
    int e = blockIdx.x * blockDim.x + threadIdx.x;
    if (e < E) atomicAdd(&hist[dst[e]], 1);
}

// ---------- dinv[i] = rsqrt(hist[i] + 1)  (self-loop adds 1) ----------
__global__ void k_dinv(const int* __restrict__ hist, float* __restrict__ dinv, int n) {
    int i = blockIdx.x * blockDim.x + threadIdx.x;
    if (i < n) dinv[i] = rsqrtf((float)(hist[i] + 1));
}

// ---------- 3-kernel exclusive scan of hist -> rowstart ----------
// scan1: each block handles 1024 elements (256 thr x 4), writes block-local
// exclusive prefix + block total.
__global__ __launch_bounds__(256) void k_scan1(const int* __restrict__ hist,
                                               int* __restrict__ rowstart,
                                               int* __restrict__ bsum, int n) {
    __shared__ int sh[256];
    const int t = threadIdx.x;
    const int base = blockIdx.x * 1024 + t * 4;
    int v0 = (base + 0 < n) ? hist[base + 0] : 0;
    int v1 = (base + 1 < n) ? hist[base + 1] : 0;
    int v2 = (base + 2 < n) ? hist[base + 2] : 0;
    int v3 = (base + 3 < n) ? hist[base + 3] : 0;
    int s = v0 + v1 + v2 + v3;
    sh[t] = s;
    __syncthreads();
    for (int off = 1; off < 256; off <<= 1) {
        int xv = (t >= off) ? sh[t - off] : 0;
        __syncthreads();
        sh[t] += xv;
        __syncthreads();
    }
    if (t == 255) bsum[blockIdx.x] = sh[255];
    int run = sh[t] - s;   // exclusive within block
    if (base + 0 < n) rowstart[base + 0] = run; run += v0;
    if (base + 1 < n) rowstart[base + 1] = run; run += v1;
    if (base + 2 < n) rowstart[base + 2] = run; run += v2;
    if (base + 3 < n) rowstart[base + 3] = run;
}

// scan2: single block turns bsum (B <= 256) into its exclusive scan
__global__ __launch_bounds__(256) void k_scan2(int* __restrict__ bsum, int B) {
    __shared__ int sh[256];
    const int t = threadIdx.x;
    int v = (t < B) ? bsum[t] : 0;
    sh[t] = v;
    __syncthreads();
    for (int off = 1; off < 256; off <<= 1) {
        int xv = (t >= off) ? sh[t - off] : 0;
        __syncthreads();
        sh[t] += xv;
        __syncthreads();
    }
    if (t < B) bsum[t] = sh[t] - v;   // exclusive
}

// scan3: add block offsets; also set rowstart[n] = E
__global__ void k_scan3(int* __restrict__ rowstart, const int* __restrict__ bsum,
                        int n, int E) {
    int i = blockIdx.x * blockDim.x + threadIdx.x;
    if (i < n) rowstart[i] += bsum[i >> 10];
    else if (i == n) rowstart[n] = E;
}

// ---------- bucket fill: srclist grouped by dst ----------
__global__ void k_fill(const int* __restrict__ ei, int E,
                       const int* __restrict__ rowstart, int* __restrict__ cursor,
                       int* __restrict__ srclist) {
    int e = blockIdx.x * blockDim.x + threadIdx.x;
    if (e >= E) return;
    int d = ei[E + e];
    int pos = atomicAdd(&cursor[d], 1);
    srclist[rowstart[d] + pos] = ei[e];
}

// ---------- pull-mode aggregation: one 64-lane wave per node ----------
__global__ __launch_bounds__(256) void k_gather(const int* __restrict__ rowstart,
                                                const int* __restrict__ srclist,
                                                const float* __restrict__ x,
                                                const float* __restrict__ dinv,
                                                float* __restrict__ out, int n) {
    const int node = blockIdx.x * 4 + (threadIdx.x >> 6);
    const int lane = threadIdx.x & 63;
    if (node >= n) return;
    const float2* X = (const float2*)x;
    const float di = dinv[node];

    float2 acc = X[(long)node * D2 + lane];       // self-loop: dinv^2 * x[node]
    float s2 = di * di;
    acc.x *= s2; acc.y *= s2;

    const int beg = rowstart[node];
    const int end = rowstart[node + 1];
    int j = beg;
    for (; j + 1 < end; j += 2) {
        int s0 = srclist[j];
        int s1 = srclist[j + 1];
        float w0 = di * dinv[s0];
        float w1 = di * dinv[s1];
        float2 v0 = X[(long)s0 * D2 + lane];
        float2 v1 = X[(long)s1 * D2 + lane];
        acc.x += w0 * v0.x + w1 * v1.x;
        acc.y += w0 * v0.y + w1 * v1.y;
    }
    if (j < end) {
        int s0 = srclist[j];
        float w0 = di * dinv[s0];
        float2 v0 = X[(long)s0 * D2 + lane];
        acc.x += w0 * v0.x;
        acc.y += w0 * v0.y;
    }
    ((float2*)out)[(long)node * D2 + lane] = acc;
}

// ---------- in-place transform: out = dropout(relu(agg @ W + b)) ----------
#define RPG 8   // rows per 32-lane group

__global__ __launch_bounds__(256) void k_transform(
        float* __restrict__ io, const float* __restrict__ W,
        const float* __restrict__ bias, const float* __restrict__ du, int n) {
    __shared__ float4 Wl[DIM * D4];   // 64 KB: Wl[k*32 + j4] = W[k][4j4..4j4+3]
    const float4* W4 = (const float4*)W;
    for (int i = threadIdx.x; i < DIM * D4; i += blockDim.x) Wl[i] = W4[i];
    __syncthreads();

    const int l = threadIdx.x & 31;   // output col group (4 cols)
    const int g = threadIdx.x >> 5;   // row group 0..7
    const float4 bb = ((const float4*)bias)[l];
    const float inv_keep = 1.0f / 0.9f;
    const long rows_per_blk = 8 * RPG;   // 64

    for (long base = (long)blockIdx.x * rows_per_blk; base < n;
         base += (long)gridDim.x * rows_per_blk) {
        long r0 = base + (long)g * RPG;
        float4 acc[RPG];
#pragma unroll
        for (int r = 0; r < RPG; ++r) acc[r] = make_float4(0.f, 0.f, 0.f, 0.f);

        for (int k4 = 0; k4 < D4; ++k4) {
            float4 w0 = Wl[(k4 * 4 + 0) * D4 + l];
            float4 w1 = Wl[(k4 * 4 + 1) * D4 + l];
            float4 w2 = Wl[(k4 * 4 + 2) * D4 + l];
            float4 w3 = Wl[(k4 * 4 + 3) * D4 + l];
#pragma unroll
            for (int r = 0; r < RPG; ++r) {
                long row = r0 + r;
                if (row < n) {
                    float4 a = ((const float4*)io)[row * D4 + k4];  // uniform per group
                    acc[r].x += a.x * w0.x + a.y * w1.x + a.z * w2.x + a.w * w3.x;
                    acc[r].y += a.x * w0.y + a.y * w1.y + a.z * w2.y + a.w * w3.y;
                    acc[r].z += a.x * w0.z + a.y * w1.z + a.z * w2.z + a.w * w3.z;
                    acc[r].w += a.x * w0.w + a.y * w1.w + a.z * w2.w + a.w * w3.w;
                }
            }
        }

#pragma unroll
        for (int r = 0; r < RPG; ++r) {
            long row = r0 + r;
            if (row < n) {
                float4 v = acc[r];
                v.x += bb.x; v.y += bb.y; v.z += bb.z; v.w += bb.w;
                float4 u = ((const float4*)du)[row * D4 + l];
                v.x = (u.x >= 0.1f) ? fmaxf(v.x, 0.f) * inv_keep : 0.f;
                v.y = (u.y >= 0.1f) ? fmaxf(v.y, 0.f) * inv_keep : 0.f;
                v.z = (u.z >= 0.1f) ? fmaxf(v.z, 0.f) * inv_keep : 0.f;
                v.w = (u.w >= 0.1f) ? fmaxf(v.w, 0.f) * inv_keep : 0.f;
                ((float4*)io)[row * D4 + l] = v;
            }
        }
    }
}

extern "C" void kernel_launch(void* const* d_in, const int* in_sizes, int n_in,
                              void* d_out, int out_size, void* d_ws, size_t ws_size,
                              hipStream_t stream) {
    const float* x  = (const float*)d_in[0];
    const int*   ei = (const int*)d_in[1];    // [2,E] int32: row0=src, row1=dst
    const float* W  = (const float*)d_in[2];
    const float* b  = (const float*)d_in[3];
    const float* du = (const float*)d_in[4];
    float* out = (float*)d_out;

    const int n = in_sizes[0] / DIM;
    const int E = in_sizes[1] / 2;

    // workspace layout (bytes)
    char* ws = (char*)d_ws;
    float* dinv     = (float*)ws;                          // N floats
    int*   hist     = (int*)(ws + ((size_t)n * 4 + 255 & ~255ull));          // N ints (reused as cursor)
    int*   rowstart = (int*)((char*)hist + ((size_t)n * 4 + 255 & ~255ull)); // N+1 ints
    int*   bsum     = (int*)((char*)rowstart + (((size_t)n + 1) * 4 + 255 & ~255ull)); // 256 ints
    int*   srclist  = (int*)((char*)bsum + 1024);          // E ints

    const int bs = 256;
    const int B = (n + 1023) / 1024;   // scan blocks (<=256 for n<=262144)

    hipMemsetAsync(hist, 0, (size_t)n * 4, stream);
    k_hist<<<(E + bs - 1) / bs, bs, 0, stream>>>(ei + E, E, hist);
    k_dinv<<<(n + bs - 1) / bs, bs, 0, stream>>>(hist, dinv, n);

    k_scan1<<<B, 256, 0, stream>>>(hist, rowstart, bsum, n);
    k_scan2<<<1, 256, 0, stream>>>(bsum, B);
    k_scan3<<<(n + 1 + bs - 1) / bs, bs, 0, stream>>>(rowstart, bsum, n, E);

    hipMemsetAsync(hist, 0, (size_t)n * 4, stream);   // hist reused as cursor
    k_fill<<<(E + bs - 1) / bs, bs, 0, stream>>>(ei, E, rowstart, hist, srclist);

    k_gather<<<(n + 3) / 4, 256, 0, stream>>>(rowstart, srclist, x, dinv, out, n);

    int blocks_t = (int)((n + 63) / 64);
    k_transform<<<blocks_t, 256, 0, stream>>>(out, W, b, du, n);
}

// Round 3
// 429.291 us; speedup vs baseline: 6.9145x; 1.2024x over previous
//
#include <hip/hip_runtime.h>

#define DIM 128
#define D4 32    // DIM/4
#define D2 64    // DIM/2

// ---------- histogram of dst (int) ----------
__global__ void k_hist(const int* __restrict__ dst, int E, int* __restrict__ hist) {
    int e = blockIdx.x * blockDim.x + threadIdx.x;
    if (e < E) atomicAdd(&hist[dst[e]], 1);
}

// ---------- dinv[i] = rsqrt(hist[i] + 1)  (self-loop adds 1) ----------
__global__ void k_dinv(const int* __restrict__ hist, float* __restrict__ dinv, int n) {
    int i = blockIdx.x * blockDim.x + threadIdx.x;
    if (i < n) dinv[i] = rsqrtf((float)(hist[i] + 1));
}

// ---------- 3-kernel exclusive scan of hist -> rowstart ----------
__global__ __launch_bounds__(256) void k_scan1(const int* __restrict__ hist,
                                               int* __restrict__ rowstart,
                                               int* __restrict__ bsum, int n) {
    __shared__ int sh[256];
    const int t = threadIdx.x;
    const int base = blockIdx.x * 1024 + t * 4;
    int v0 = (base + 0 < n) ? hist[base + 0] : 0;
    int v1 = (base + 1 < n) ? hist[base + 1] : 0;
    int v2 = (base + 2 < n) ? hist[base + 2] : 0;
    int v3 = (base + 3 < n) ? hist[base + 3] : 0;
    int s = v0 + v1 + v2 + v3;
    sh[t] = s;
    __syncthreads();
    for (int off = 1; off < 256; off <<= 1) {
        int xv = (t >= off) ? sh[t - off] : 0;
        __syncthreads();
        sh[t] += xv;
        __syncthreads();
    }
    if (t == 255) bsum[blockIdx.x] = sh[255];
    int run = sh[t] - s;   // exclusive within block
    if (base + 0 < n) rowstart[base + 0] = run; run += v0;
    if (base + 1 < n) rowstart[base + 1] = run; run += v1;
    if (base + 2 < n) rowstart[base + 2] = run; run += v2;
    if (base + 3 < n) rowstart[base + 3] = run;
}

__global__ __launch_bounds__(256) void k_scan2(int* __restrict__ bsum, int B) {
    __shared__ int sh[256];
    const int t = threadIdx.x;
    int v = (t < B) ? bsum[t] : 0;
    sh[t] = v;
    __syncthreads();
    for (int off = 1; off < 256; off <<= 1) {
        int xv = (t >= off) ? sh[t - off] : 0;
        __syncthreads();
        sh[t] += xv;
        __syncthreads();
    }
    if (t < B) bsum[t] = sh[t] - v;   // exclusive
}

__global__ void k_scan3(int* __restrict__ rowstart, const int* __restrict__ bsum,
                        int n, int E) {
    int i = blockIdx.x * blockDim.x + threadIdx.x;
    if (i < n) rowstart[i] += bsum[i >> 10];
    else if (i == n) rowstart[n] = E;
}

// ---------- bucket fill: srclist grouped by dst ----------
__global__ void k_fill(const int* __restrict__ ei, int E,
                       const int* __restrict__ rowstart, int* __restrict__ cursor,
                       int* __restrict__ srclist) {
    int e = blockIdx.x * blockDim.x + threadIdx.x;
    if (e >= E) return;
    int d = ei[E + e];
    int pos = atomicAdd(&cursor[d], 1);
    srclist[rowstart[d] + pos] = ei[e];
}

// ---------- pull-mode aggregation: one 64-lane wave per node ----------
__global__ __launch_bounds__(256) void k_gather(const int* __restrict__ rowstart,
                                                const int* __restrict__ srclist,
                                                const float* __restrict__ x,
                                                const float* __restrict__ dinv,
                                                float* __restrict__ out, int n) {
    const int node = blockIdx.x * 4 + (threadIdx.x >> 6);
    const int lane = threadIdx.x & 63;
    if (node >= n) return;
    const float2* X = (const float2*)x;
    const float di = dinv[node];

    float2 acc = X[(long)node * D2 + lane];       // self-loop: dinv^2 * x[node]
    float s2 = di * di;
    acc.x *= s2; acc.y *= s2;

    const int beg = rowstart[node];
    const int end = rowstart[node + 1];
    int j = beg;
    for (; j + 1 < end; j += 2) {
        int s0 = srclist[j];
        int s1 = srclist[j + 1];
        float w0 = di * dinv[s0];
        float w1 = di * dinv[s1];
        float2 v0 = X[(long)s0 * D2 + lane];
        float2 v1 = X[(long)s1 * D2 + lane];
        acc.x += w0 * v0.x + w1 * v1.x;
        acc.y += w0 * v0.y + w1 * v1.y;
    }
    if (j < end) {
        int s0 = srclist[j];
        float w0 = di * dinv[s0];
        float2 v0 = X[(long)s0 * D2 + lane];
        acc.x += w0 * v0.x;
        acc.y += w0 * v0.y;
    }
    ((float2*)out)[(long)node * D2 + lane] = acc;
}

// ---------- in-place transform: out = dropout(relu(agg @ W + b)) ----------
// Split-K: W staged in two 32KB halves so 5 blocks/CU fit (occupancy ~60%).
#define RPG 8   // rows per 32-lane group

__global__ __launch_bounds__(256, 5) void k_transform(
        float* __restrict__ io, const float* __restrict__ W,
        const float* __restrict__ bias, const float* __restrict__ du, int n) {
    __shared__ float4 Wl[64 * D4];   // 32 KB: half of W
    const float4* W4 = (const float4*)W;

    const int l = threadIdx.x & 31;   // output col group (4 cols)
    const int g = threadIdx.x >> 5;   // row group 0..7
    const float4 bb = ((const float4*)bias)[l];
    const float inv_keep = 1.0f / 0.9f;

    long r0 = (long)blockIdx.x * 64 + (long)g * RPG;

    float4 acc[RPG];
#pragma unroll
    for (int r = 0; r < RPG; ++r) acc[r] = make_float4(0.f, 0.f, 0.f, 0.f);

    for (int half = 0; half < 2; ++half) {
        __syncthreads();   // protect Wl from previous phase's readers
        for (int i = threadIdx.x; i < 64 * D4; i += 256)
            Wl[i] = W4[half * 64 * D4 + i];
        __syncthreads();

        const int kb = half * 16;   // float4-k offset into A rows
#pragma unroll 4
        for (int k4 = 0; k4 < 16; ++k4) {
            float4 w0 = Wl[(k4 * 4 + 0) * D4 + l];
            float4 w1 = Wl[(k4 * 4 + 1) * D4 + l];
            float4 w2 = Wl[(k4 * 4 + 2) * D4 + l];
            float4 w3 = Wl[(k4 * 4 + 3) * D4 + l];
#pragma unroll
            for (int r = 0; r < RPG; ++r) {
                long row = r0 + r;
                if (row < n) {
                    float4 a = ((const float4*)io)[row * D4 + kb + k4];
                    acc[r].x += a.x * w0.x + a.y * w1.x + a.z * w2.x + a.w * w3.x;
                    acc[r].y += a.x * w0.y + a.y * w1.y + a.z * w2.y + a.w * w3.y;
                    acc[r].z += a.x * w0.z + a.y * w1.z + a.z * w2.z + a.w * w3.z;
                    acc[r].w += a.x * w0.w + a.y * w1.w + a.z * w2.w + a.w * w3.w;
                }
            }
        }
    }

#pragma unroll
    for (int r = 0; r < RPG; ++r) {
        long row = r0 + r;
        if (row < n) {
            float4 v = acc[r];
            v.x += bb.x; v.y += bb.y; v.z += bb.z; v.w += bb.w;
            float4 u = ((const float4*)du)[row * D4 + l];
            v.x = (u.x >= 0.1f) ? fmaxf(v.x, 0.f) * inv_keep : 0.f;
            v.y = (u.y >= 0.1f) ? fmaxf(v.y, 0.f) * inv_keep : 0.f;
            v.z = (u.z >= 0.1f) ? fmaxf(v.z, 0.f) * inv_keep : 0.f;
            v.w = (u.w >= 0.1f) ? fmaxf(v.w, 0.f) * inv_keep : 0.f;
            ((float4*)io)[row * D4 + l] = v;
        }
    }
}

extern "C" void kernel_launch(void* const* d_in, const int* in_sizes, int n_in,
                              void* d_out, int out_size, void* d_ws, size_t ws_size,
                              hipStream_t stream) {
    const float* x  = (const float*)d_in[0];
    const int*   ei = (const int*)d_in[1];    // [2,E] int32: row0=src, row1=dst
    const float* W  = (const float*)d_in[2];
    const float* b  = (const float*)d_in[3];
    const float* du = (const float*)d_in[4];
    float* out = (float*)d_out;

    const int n = in_sizes[0] / DIM;
    const int E = in_sizes[1] / 2;

    // workspace layout (bytes)
    char* ws = (char*)d_ws;
    float* dinv     = (float*)ws;                          // N floats
    int*   hist     = (int*)(ws + ((size_t)n * 4 + 255 & ~255ull));          // N ints (reused as cursor)
    int*   rowstart = (int*)((char*)hist + ((size_t)n * 4 + 255 & ~255ull)); // N+1 ints
    int*   bsum     = (int*)((char*)rowstart + (((size_t)n + 1) * 4 + 255 & ~255ull)); // 256 ints
    int*   srclist  = (int*)((char*)bsum + 1024);          // E ints

    const int bs = 256;
    const int B = (n + 1023) / 1024;   // scan blocks (<=256 for n<=262144)

    hipMemsetAsync(hist, 0, (size_t)n * 4, stream);
    k_hist<<<(E + bs - 1) / bs, bs, 0, stream>>>(ei + E, E, hist);
    k_dinv<<<(n + bs - 1) / bs, bs, 0, stream>>>(hist, dinv, n);

    k_scan1<<<B, 256, 0, stream>>>(hist, rowstart, bsum, n);
    k_scan2<<<1, 256, 0, stream>>>(bsum, B);
    k_scan3<<<(n + 1 + bs - 1) / bs, bs, 0, stream>>>(rowstart, bsum, n, E);

    hipMemsetAsync(hist, 0, (size_t)n * 4, stream);   // hist reused as cursor
    k_fill<<<(E + bs - 1) / bs, bs, 0, stream>>>(ei, E, rowstart, hist, srclist);

    k_gather<<<(n + 3) / 4, 256, 0, stream>>>(rowstart, srclist, x, dinv, out, n);

    int blocks_t = (int)((n + 63) / 64);
    k_transform<<<blocks_t, 256, 0, stream>>>(out, W, b, du, n);
}

// Round 4
// 363.551 us; speedup vs baseline: 8.1648x; 1.1808x over previous
//
#include <hip/hip_runtime.h>

#define DIM 128
#define D4 32    // DIM/4
#define D2 64    // DIM/2

// ---------- histogram of dst (int) ----------
__global__ void k_hist(const int* __restrict__ dst, int E, int* __restrict__ hist) {
    int e = blockIdx.x * blockDim.x + threadIdx.x;
    if (e < E) atomicAdd(&hist[dst[e]], 1);
}

// ---------- dinv[i] = rsqrt(hist[i] + 1)  (self-loop adds 1) ----------
__global__ void k_dinv(const int* __restrict__ hist, float* __restrict__ dinv, int n) {
    int i = blockIdx.x * blockDim.x + threadIdx.x;
    if (i < n) dinv[i] = rsqrtf((float)(hist[i] + 1));
}

// ---------- xs[i] = bf16(dinv[i] * x[i])  (pre-scaled gather payload) ----------
__device__ __forceinline__ unsigned pack_bf16(float a, float b) {
    unsigned ua = __float_as_uint(a);
    unsigned ub = __float_as_uint(b);
    ua = (ua + 0x7FFFu + ((ua >> 16) & 1u)) >> 16;        // RNE
    ub = (ub + 0x7FFFu + ((ub >> 16) & 1u)) & 0xFFFF0000u;
    return ua | ub;   // lo = a, hi = b
}

__global__ __launch_bounds__(256) void k_xprep(const float* __restrict__ x,
                                               const float* __restrict__ dinv,
                                               unsigned* __restrict__ xs, int n) {
    long t = (long)blockIdx.x * blockDim.x + threadIdx.x;   // one per float4
    long total = (long)n * D4;
    if (t >= total) return;
    int row = (int)(t >> 5);
    float di = dinv[row];
    float4 v = ((const float4*)x)[t];
    uint2 o;
    o.x = pack_bf16(v.x * di, v.y * di);
    o.y = pack_bf16(v.z * di, v.w * di);
    ((uint2*)xs)[t] = o;
}

// ---------- 3-kernel exclusive scan of hist -> rowstart ----------
__global__ __launch_bounds__(256) void k_scan1(const int* __restrict__ hist,
                                               int* __restrict__ rowstart,
                                               int* __restrict__ bsum, int n) {
    __shared__ int sh[256];
    const int t = threadIdx.x;
    const int base = blockIdx.x * 1024 + t * 4;
    int v0 = (base + 0 < n) ? hist[base + 0] : 0;
    int v1 = (base + 1 < n) ? hist[base + 1] : 0;
    int v2 = (base + 2 < n) ? hist[base + 2] : 0;
    int v3 = (base + 3 < n) ? hist[base + 3] : 0;
    int s = v0 + v1 + v2 + v3;
    sh[t] = s;
    __syncthreads();
    for (int off = 1; off < 256; off <<= 1) {
        int xv = (t >= off) ? sh[t - off] : 0;
        __syncthreads();
        sh[t] += xv;
        __syncthreads();
    }
    if (t == 255) bsum[blockIdx.x] = sh[255];
    int run = sh[t] - s;   // exclusive within block
    if (base + 0 < n) rowstart[base + 0] = run; run += v0;
    if (base + 1 < n) rowstart[base + 1] = run; run += v1;
    if (base + 2 < n) rowstart[base + 2] = run; run += v2;
    if (base + 3 < n) rowstart[base + 3] = run;
}

__global__ __launch_bounds__(256) void k_scan2(int* __restrict__ bsum, int B) {
    __shared__ int sh[256];
    const int t = threadIdx.x;
    int v = (t < B) ? bsum[t] : 0;
    sh[t] = v;
    __syncthreads();
    for (int off = 1; off < 256; off <<= 1) {
        int xv = (t >= off) ? sh[t - off] : 0;
        __syncthreads();
        sh[t] += xv;
        __syncthreads();
    }
    if (t < B) bsum[t] = sh[t] - v;   // exclusive
}

__global__ void k_scan3(int* __restrict__ rowstart, const int* __restrict__ bsum,
                        int n, int E) {
    int i = blockIdx.x * blockDim.x + threadIdx.x;
    if (i < n) rowstart[i] += bsum[i >> 10];
    else if (i == n) rowstart[n] = E;
}

// ---------- bucket fill: srclist grouped by dst ----------
__global__ void k_fill(const int* __restrict__ ei, int E,
                       const int* __restrict__ rowstart, int* __restrict__ cursor,
                       int* __restrict__ srclist) {
    int e = blockIdx.x * blockDim.x + threadIdx.x;
    if (e >= E) return;
    int d = ei[E + e];
    int pos = atomicAdd(&cursor[d], 1);
    srclist[rowstart[d] + pos] = ei[e];
}

// ---------- pull-mode aggregation, bf16 payload, 4-deep pipeline ----------
// lane l of the wave owns features 2l, 2l+1 (one packed uint per row)
__global__ __launch_bounds__(256) void k_gather_bf(const int* __restrict__ rowstart,
                                                   const int* __restrict__ srclist,
                                                   const unsigned* __restrict__ xs,
                                                   const float* __restrict__ dinv,
                                                   float* __restrict__ out, int n) {
    const int node = blockIdx.x * 4 + (threadIdx.x >> 6);
    const int lane = threadIdx.x & 63;
    if (node >= n) return;
    const float di = dinv[node];

    // self-loop: di * xs[node]  (xs already has one dinv factor)
    unsigned sv = xs[(long)node * D2 + lane];
    float2 acc;
    acc.x = __uint_as_float(sv << 16);
    acc.y = __uint_as_float(sv & 0xFFFF0000u);

    const int beg = rowstart[node];
    const int end = rowstart[node + 1];
    int j = beg;
    for (; j + 3 < end; j += 4) {
        int s0 = srclist[j];
        int s1 = srclist[j + 1];
        int s2 = srclist[j + 2];
        int s3 = srclist[j + 3];
        unsigned v0 = xs[(long)s0 * D2 + lane];
        unsigned v1 = xs[(long)s1 * D2 + lane];
        unsigned v2 = xs[(long)s2 * D2 + lane];
        unsigned v3 = xs[(long)s3 * D2 + lane];
        acc.x += __uint_as_float(v0 << 16) + __uint_as_float(v1 << 16)
               + __uint_as_float(v2 << 16) + __uint_as_float(v3 << 16);
        acc.y += __uint_as_float(v0 & 0xFFFF0000u) + __uint_as_float(v1 & 0xFFFF0000u)
               + __uint_as_float(v2 & 0xFFFF0000u) + __uint_as_float(v3 & 0xFFFF0000u);
    }
    for (; j < end; ++j) {
        unsigned v0 = xs[(long)srclist[j] * D2 + lane];
        acc.x += __uint_as_float(v0 << 16);
        acc.y += __uint_as_float(v0 & 0xFFFF0000u);
    }
    acc.x *= di; acc.y *= di;
    ((float2*)out)[(long)node * D2 + lane] = acc;
}

// ---------- fallback f32 gather (if ws too small for xs) ----------
__global__ __launch_bounds__(256) void k_gather(const int* __restrict__ rowstart,
                                                const int* __restrict__ srclist,
                                                const float* __restrict__ x,
                                                const float* __restrict__ dinv,
                                                float* __restrict__ out, int n) {
    const int node = blockIdx.x * 4 + (threadIdx.x >> 6);
    const int lane = threadIdx.x & 63;
    if (node >= n) return;
    const float2* X = (const float2*)x;
    const float di = dinv[node];

    float2 acc = X[(long)node * D2 + lane];
    float s2 = di * di;
    acc.x *= s2; acc.y *= s2;

    const int beg = rowstart[node];
    const int end = rowstart[node + 1];
    int j = beg;
    for (; j + 1 < end; j += 2) {
        int s0 = srclist[j];
        int s1 = srclist[j + 1];
        float w0 = di * dinv[s0];
        float w1 = di * dinv[s1];
        float2 v0 = X[(long)s0 * D2 + lane];
        float2 v1 = X[(long)s1 * D2 + lane];
        acc.x += w0 * v0.x + w1 * v1.x;
        acc.y += w0 * v0.y + w1 * v1.y;
    }
    if (j < end) {
        int s0 = srclist[j];
        float w0 = di * dinv[s0];
        float2 v0 = X[(long)s0 * D2 + lane];
        acc.x += w0 * v0.x;
        acc.y += w0 * v0.y;
    }
    ((float2*)out)[(long)node * D2 + lane] = acc;
}

// ---------- in-place transform: out = dropout(relu(agg @ W + b)) ----------
#define RPG 8   // rows per 32-lane group

__global__ __launch_bounds__(256, 5) void k_transform(
        float* __restrict__ io, const float* __restrict__ W,
        const float* __restrict__ bias, const float* __restrict__ du, int n) {
    __shared__ float4 Wl[64 * D4];   // 32 KB: half of W
    const float4* W4 = (const float4*)W;

    const int l = threadIdx.x & 31;   // output col group (4 cols)
    const int g = threadIdx.x >> 5;   // row group 0..7
    const float4 bb = ((const float4*)bias)[l];
    const float inv_keep = 1.0f / 0.9f;

    long r0 = (long)blockIdx.x * 64 + (long)g * RPG;

    float4 acc[RPG];
#pragma unroll
    for (int r = 0; r < RPG; ++r) acc[r] = make_float4(0.f, 0.f, 0.f, 0.f);

    for (int half = 0; half < 2; ++half) {
        __syncthreads();   // protect Wl from previous phase's readers
        for (int i = threadIdx.x; i < 64 * D4; i += 256)
            Wl[i] = W4[half * 64 * D4 + i];
        __syncthreads();

        const int kb = half * 16;   // float4-k offset into A rows
#pragma unroll 4
        for (int k4 = 0; k4 < 16; ++k4) {
            float4 w0 = Wl[(k4 * 4 + 0) * D4 + l];
            float4 w1 = Wl[(k4 * 4 + 1) * D4 + l];
            float4 w2 = Wl[(k4 * 4 + 2) * D4 + l];
            float4 w3 = Wl[(k4 * 4 + 3) * D4 + l];
#pragma unroll
            for (int r = 0; r < RPG; ++r) {
                long row = r0 + r;
                if (row < n) {
                    float4 a = ((const float4*)io)[row * D4 + kb + k4];
                    acc[r].x += a.x * w0.x + a.y * w1.x + a.z * w2.x + a.w * w3.x;
                    acc[r].y += a.x * w0.y + a.y * w1.y + a.z * w2.y + a.w * w3.y;
                    acc[r].z += a.x * w0.z + a.y * w1.z + a.z * w2.z + a.w * w3.z;
                    acc[r].w += a.x * w0.w + a.y * w1.w + a.z * w2.w + a.w * w3.w;
                }
            }
        }
    }

#pragma unroll
    for (int r = 0; r < RPG; ++r) {
        long row = r0 + r;
        if (row < n) {
            float4 v = acc[r];
            v.x += bb.x; v.y += bb.y; v.z += bb.z; v.w += bb.w;
            float4 u = ((const float4*)du)[row * D4 + l];
            v.x = (u.x >= 0.1f) ? fmaxf(v.x, 0.f) * inv_keep : 0.f;
            v.y = (u.y >= 0.1f) ? fmaxf(v.y, 0.f) * inv_keep : 0.f;
            v.z = (u.z >= 0.1f) ? fmaxf(v.z, 0.f) * inv_keep : 0.f;
            v.w = (u.w >= 0.1f) ? fmaxf(v.w, 0.f) * inv_keep : 0.f;
            ((float4*)io)[row * D4 + l] = v;
        }
    }
}

extern "C" void kernel_launch(void* const* d_in, const int* in_sizes, int n_in,
                              void* d_out, int out_size, void* d_ws, size_t ws_size,
                              hipStream_t stream) {
    const float* x  = (const float*)d_in[0];
    const int*   ei = (const int*)d_in[1];    // [2,E] int32: row0=src, row1=dst
    const float* W  = (const float*)d_in[2];
    const float* b  = (const float*)d_in[3];
    const float* du = (const float*)d_in[4];
    float* out = (float*)d_out;

    const int n = in_sizes[0] / DIM;
    const int E = in_sizes[1] / 2;

    // workspace layout (256B-aligned slabs)
    auto al = [](size_t v) { return (v + 255) & ~(size_t)255; };
    char* ws = (char*)d_ws;
    size_t o_dinv = 0;
    size_t o_hist = o_dinv + al((size_t)n * 4);
    size_t o_rs   = o_hist + al((size_t)n * 4);
    size_t o_bsum = o_rs   + al(((size_t)n + 1) * 4);
    size_t o_src  = o_bsum + 1024;
    size_t o_xs   = o_src  + al((size_t)E * 4);
    size_t need_bf = o_xs + (size_t)n * DIM * 2;   // xs: N*128 bf16

    float* dinv     = (float*)(ws + o_dinv);
    int*   hist     = (int*)(ws + o_hist);
    int*   rowstart = (int*)(ws + o_rs);
    int*   bsum     = (int*)(ws + o_bsum);
    int*   srclist  = (int*)(ws + o_src);
    unsigned* xs    = (unsigned*)(ws + o_xs);
    const bool use_bf = (ws_size >= need_bf);

    const int bs = 256;
    const int B = (n + 1023) / 1024;   // scan blocks (<=256 for n<=262144)

    hipMemsetAsync(hist, 0, (size_t)n * 4, stream);
    k_hist<<<(E + bs - 1) / bs, bs, 0, stream>>>(ei + E, E, hist);
    k_dinv<<<(n + bs - 1) / bs, bs, 0, stream>>>(hist, dinv, n);

    k_scan1<<<B, 256, 0, stream>>>(hist, rowstart, bsum, n);
    k_scan2<<<1, 256, 0, stream>>>(bsum, B);
    k_scan3<<<(n + 1 + bs - 1) / bs, bs, 0, stream>>>(rowstart, bsum, n, E);

    hipMemsetAsync(hist, 0, (size_t)n * 4, stream);   // hist reused as cursor
    k_fill<<<(E + bs - 1) / bs, bs, 0, stream>>>(ei, E, rowstart, hist, srclist);

    if (use_bf) {
        long t_x = (long)n * D4;
        k_xprep<<<(int)((t_x + bs - 1) / bs), bs, 0, stream>>>(x, dinv, xs, n);
        k_gather_bf<<<(n + 3) / 4, 256, 0, stream>>>(rowstart, srclist, xs, dinv, out, n);
    } else {
        k_gather<<<(n + 3) / 4, 256, 0, stream>>>(rowstart, srclist, x, dinv, out, n);
    }

    int blocks_t = (int)((n + 63) / 64);
    k_transform<<<blocks_t, 256, 0, stream>>>(out, W, b, du, n);
}

// Round 5
// 283.768 us; speedup vs baseline: 10.4603x; 1.2812x over previous
//
#include <hip/hip_runtime.h>

#define DIM 128
#define D4 32    // DIM/4
#define D2 64    // DIM/2

typedef short short8 __attribute__((ext_vector_type(8)));   // 8 bf16 in 4 VGPRs
typedef float f32x4 __attribute__((ext_vector_type(4)));

// ---------- histogram of dst (int) ----------
__global__ void k_hist(const int* __restrict__ dst, int E, int* __restrict__ hist) {
    int e = blockIdx.x * blockDim.x + threadIdx.x;
    if (e < E) atomicAdd(&hist[dst[e]], 1);
}

// ---------- dinv[i] = rsqrt(hist[i] + 1)  (self-loop adds 1) ----------
__global__ void k_dinv(const int* __restrict__ hist, float* __restrict__ dinv, int n) {
    int i = blockIdx.x * blockDim.x + threadIdx.x;
    if (i < n) dinv[i] = rsqrtf((float)(hist[i] + 1));
}

// ---------- bf16 helpers (RNE) ----------
__device__ __forceinline__ unsigned pack_bf16(float a, float b) {
    unsigned ua = __float_as_uint(a);
    unsigned ub = __float_as_uint(b);
    ua = (ua + 0x7FFFu + ((ua >> 16) & 1u)) >> 16;        // RNE
    ub = (ub + 0x7FFFu + ((ub >> 16) & 1u)) & 0xFFFF0000u;
    return ua | ub;   // lo = a, hi = b
}
__device__ __forceinline__ unsigned short bf16_of(float a) {
    unsigned ua = __float_as_uint(a);
    return (unsigned short)((ua + 0x7FFFu + ((ua >> 16) & 1u)) >> 16);
}

// ---------- xs[i] = bf16(dinv[i] * x[i])  (pre-scaled gather payload) ----------
__global__ __launch_bounds__(256) void k_xprep(const float* __restrict__ x,
                                               const float* __restrict__ dinv,
                                               unsigned* __restrict__ xs, int n) {
    long t = (long)blockIdx.x * blockDim.x + threadIdx.x;   // one per float4
    long total = (long)n * D4;
    if (t >= total) return;
    int row = (int)(t >> 5);
    float di = dinv[row];
    float4 v = ((const float4*)x)[t];
    uint2 o;
    o.x = pack_bf16(v.x * di, v.y * di);
    o.y = pack_bf16(v.z * di, v.w * di);
    ((uint2*)xs)[t] = o;
}

// ---------- W^T in bf16: wt[j*128 + k] = bf16(W[k*128 + j]) ----------
__global__ __launch_bounds__(256) void k_wprep(const float* __restrict__ W,
                                               unsigned short* __restrict__ wt) {
    int o = blockIdx.x * blockDim.x + threadIdx.x;   // 16384 threads
    if (o >= DIM * DIM) return;
    int j = o >> 7, k = o & 127;
    wt[o] = bf16_of(W[k * DIM + j]);
}

// ---------- 3-kernel exclusive scan of hist -> rowstart ----------
__global__ __launch_bounds__(256) void k_scan1(const int* __restrict__ hist,
                                               int* __restrict__ rowstart,
                                               int* __restrict__ bsum, int n) {
    __shared__ int sh[256];
    const int t = threadIdx.x;
    const int base = blockIdx.x * 1024 + t * 4;
    int v0 = (base + 0 < n) ? hist[base + 0] : 0;
    int v1 = (base + 1 < n) ? hist[base + 1] : 0;
    int v2 = (base + 2 < n) ? hist[base + 2] : 0;
    int v3 = (base + 3 < n) ? hist[base + 3] : 0;
    int s = v0 + v1 + v2 + v3;
    sh[t] = s;
    __syncthreads();
    for (int off = 1; off < 256; off <<= 1) {
        int xv = (t >= off) ? sh[t - off] : 0;
        __syncthreads();
        sh[t] += xv;
        __syncthreads();
    }
    if (t == 255) bsum[blockIdx.x] = sh[255];
    int run = sh[t] - s;   // exclusive within block
    if (base + 0 < n) rowstart[base + 0] = run; run += v0;
    if (base + 1 < n) rowstart[base + 1] = run; run += v1;
    if (base + 2 < n) rowstart[base + 2] = run; run += v2;
    if (base + 3 < n) rowstart[base + 3] = run;
}

__global__ __launch_bounds__(256) void k_scan2(int* __restrict__ bsum, int B) {
    __shared__ int sh[256];
    const int t = threadIdx.x;
    int v = (t < B) ? bsum[t] : 0;
    sh[t] = v;
    __syncthreads();
    for (int off = 1; off < 256; off <<= 1) {
        int xv = (t >= off) ? sh[t - off] : 0;
        __syncthreads();
        sh[t] += xv;
        __syncthreads();
    }
    if (t < B) bsum[t] = sh[t] - v;   // exclusive
}

__global__ void k_scan3(int* __restrict__ rowstart, const int* __restrict__ bsum,
                        int n, int E) {
    int i = blockIdx.x * blockDim.x + threadIdx.x;
    if (i < n) rowstart[i] += bsum[i >> 10];
    else if (i == n) rowstart[n] = E;
}

// ---------- bucket fill: srclist grouped by dst ----------
__global__ void k_fill(const int* __restrict__ ei, int E,
                       const int* __restrict__ rowstart, int* __restrict__ cursor,
                       int* __restrict__ srclist) {
    int e = blockIdx.x * blockDim.x + threadIdx.x;
    if (e >= E) return;
    int d = ei[E + e];
    int pos = atomicAdd(&cursor[d], 1);
    srclist[rowstart[d] + pos] = ei[e];
}

// ---------- pull aggregation, bf16 in / bf16 out (to ws) ----------
__global__ __launch_bounds__(256) void k_gather_bb(const int* __restrict__ rowstart,
                                                   const int* __restrict__ srclist,
                                                   const unsigned* __restrict__ xs,
                                                   const float* __restrict__ dinv,
                                                   unsigned* __restrict__ agg, int n) {
    const int node = blockIdx.x * 4 + (threadIdx.x >> 6);
    const int lane = threadIdx.x & 63;
    if (node >= n) return;
    const float di = dinv[node];

    unsigned sv = xs[(long)node * D2 + lane];   // self-loop (has one dinv factor)
    float2 acc;
    acc.x = __uint_as_float(sv << 16);
    acc.y = __uint_as_float(sv & 0xFFFF0000u);

    const int beg = rowstart[node];
    const int end = rowstart[node + 1];
    int j = beg;
    for (; j + 3 < end; j += 4) {
        int s0 = srclist[j];
        int s1 = srclist[j + 1];
        int s2 = srclist[j + 2];
        int s3 = srclist[j + 3];
        unsigned v0 = xs[(long)s0 * D2 + lane];
        unsigned v1 = xs[(long)s1 * D2 + lane];
        unsigned v2 = xs[(long)s2 * D2 + lane];
        unsigned v3 = xs[(long)s3 * D2 + lane];
        acc.x += __uint_as_float(v0 << 16) + __uint_as_float(v1 << 16)
               + __uint_as_float(v2 << 16) + __uint_as_float(v3 << 16);
        acc.y += __uint_as_float(v0 & 0xFFFF0000u) + __uint_as_float(v1 & 0xFFFF0000u)
               + __uint_as_float(v2 & 0xFFFF0000u) + __uint_as_float(v3 & 0xFFFF0000u);
    }
    for (; j < end; ++j) {
        unsigned v0 = xs[(long)srclist[j] * D2 + lane];
        acc.x += __uint_as_float(v0 << 16);
        acc.y += __uint_as_float(v0 & 0xFFFF0000u);
    }
    agg[(long)node * D2 + lane] = pack_bf16(acc.x * di, acc.y * di);
}

// ---------- bf16-out gather to d_out (tier1: f32 out) ----------
__global__ __launch_bounds__(256) void k_gather_bf(const int* __restrict__ rowstart,
                                                   const int* __restrict__ srclist,
                                                   const unsigned* __restrict__ xs,
                                                   const float* __restrict__ dinv,
                                                   float* __restrict__ out, int n) {
    const int node = blockIdx.x * 4 + (threadIdx.x >> 6);
    const int lane = threadIdx.x & 63;
    if (node >= n) return;
    const float di = dinv[node];
    unsigned sv = xs[(long)node * D2 + lane];
    float2 acc;
    acc.x = __uint_as_float(sv << 16);
    acc.y = __uint_as_float(sv & 0xFFFF0000u);
    const int beg = rowstart[node];
    const int end = rowstart[node + 1];
    int j = beg;
    for (; j + 3 < end; j += 4) {
        int s0 = srclist[j]; int s1 = srclist[j + 1];
        int s2 = srclist[j + 2]; int s3 = srclist[j + 3];
        unsigned v0 = xs[(long)s0 * D2 + lane];
        unsigned v1 = xs[(long)s1 * D2 + lane];
        unsigned v2 = xs[(long)s2 * D2 + lane];
        unsigned v3 = xs[(long)s3 * D2 + lane];
        acc.x += __uint_as_float(v0 << 16) + __uint_as_float(v1 << 16)
               + __uint_as_float(v2 << 16) + __uint_as_float(v3 << 16);
        acc.y += __uint_as_float(v0 & 0xFFFF0000u) + __uint_as_float(v1 & 0xFFFF0000u)
               + __uint_as_float(v2 & 0xFFFF0000u) + __uint_as_float(v3 & 0xFFFF0000u);
    }
    for (; j < end; ++j) {
        unsigned v0 = xs[(long)srclist[j] * D2 + lane];
        acc.x += __uint_as_float(v0 << 16);
        acc.y += __uint_as_float(v0 & 0xFFFF0000u);
    }
    acc.x *= di; acc.y *= di;
    ((float2*)out)[(long)node * D2 + lane] = acc;
}

// ---------- MFMA transform: out = dropout(relu(A @ W + b)), A bf16, W^T bf16 ----------
// block = 4 waves; wave covers 16 rows x 64 cols; block = 32 rows x 128 cols.
// grid-stride over 32-row tiles.
__global__ __launch_bounds__(256) void k_mfma_transform(
        const unsigned short* __restrict__ A,    // bf16 [n][128]
        const unsigned short* __restrict__ WT,   // bf16 [128 cols][128 k]
        const float* __restrict__ bias,
        const float* __restrict__ du,
        float* __restrict__ out, int n, int ntiles) {
    const int wave  = threadIdx.x >> 6;
    const int lane  = threadIdx.x & 63;
    const int rhalf = wave >> 1;            // which 16-row half of the 32-row tile
    const int cg    = wave & 1;             // which 64-col group
    const int lr    = lane & 15;
    const int lk8   = (lane >> 4) * 8;      // k-offset within a 32-wide k-step

    // resident B fragments: bfr[ct][ks]
    short8 bfr[4][4];
    float  bcol[4];
#pragma unroll
    for (int ct = 0; ct < 4; ++ct) {
        int col = cg * 64 + ct * 16 + lr;
        bcol[ct] = bias[col];
#pragma unroll
        for (int ks = 0; ks < 4; ++ks)
            bfr[ct][ks] = *reinterpret_cast<const short8*>(WT + col * DIM + ks * 32 + lk8);
    }

    for (int t = blockIdx.x; t < ntiles; t += gridDim.x) {
        const long row0 = (long)t * 32 + rhalf * 16;
        long ar = row0 + lr; if (ar >= n) ar = n - 1;
        short8 afr[4];
#pragma unroll
        for (int ks = 0; ks < 4; ++ks)
            afr[ks] = *reinterpret_cast<const short8*>(A + ar * DIM + ks * 32 + lk8);

#pragma unroll
        for (int ct = 0; ct < 4; ++ct) {
            f32x4 acc = {0.f, 0.f, 0.f, 0.f};
#pragma unroll
            for (int ks = 0; ks < 4; ++ks)
                acc = __builtin_amdgcn_mfma_f32_16x16x32_bf16(afr[ks], bfr[ct][ks], acc, 0, 0, 0);
            // epilogue for this 16x16 tile
            const int gcol = cg * 64 + ct * 16 + lr;
            const long rbase = row0 + (lane >> 4) * 4;
#pragma unroll
            for (int r = 0; r < 4; ++r) {
                long grow = rbase + r;
                if (grow < n) {
                    float v = acc[r] + bcol[ct];
                    float u = du[grow * DIM + gcol];
                    v = (u >= 0.1f) ? fmaxf(v, 0.f) * (1.0f / 0.9f) : 0.f;
                    out[grow * DIM + gcol] = v;
                }
            }
        }
    }
}

// ---------- tier-1 VALU transform (in-place f32) ----------
#define RPG 8
__global__ __launch_bounds__(256, 5) void k_transform(
        float* __restrict__ io, const float* __restrict__ W,
        const float* __restrict__ bias, const float* __restrict__ du, int n) {
    __shared__ float4 Wl[64 * D4];
    const float4* W4 = (const float4*)W;
    const int l = threadIdx.x & 31;
    const int g = threadIdx.x >> 5;
    const float4 bb = ((const float4*)bias)[l];
    const float inv_keep = 1.0f / 0.9f;
    long r0 = (long)blockIdx.x * 64 + (long)g * RPG;
    float4 acc[RPG];
#pragma unroll
    for (int r = 0; r < RPG; ++r) acc[r] = make_float4(0.f, 0.f, 0.f, 0.f);
    for (int half = 0; half < 2; ++half) {
        __syncthreads();
        for (int i = threadIdx.x; i < 64 * D4; i += 256)
            Wl[i] = W4[half * 64 * D4 + i];
        __syncthreads();
        const int kb = half * 16;
#pragma unroll 4
        for (int k4 = 0; k4 < 16; ++k4) {
            float4 w0 = Wl[(k4 * 4 + 0) * D4 + l];
            float4 w1 = Wl[(k4 * 4 + 1) * D4 + l];
            float4 w2 = Wl[(k4 * 4 + 2) * D4 + l];
            float4 w3 = Wl[(k4 * 4 + 3) * D4 + l];
#pragma unroll
            for (int r = 0; r < RPG; ++r) {
                long row = r0 + r;
                if (row < n) {
                    float4 a = ((const float4*)io)[row * D4 + kb + k4];
                    acc[r].x += a.x * w0.x + a.y * w1.x + a.z * w2.x + a.w * w3.x;
                    acc[r].y += a.x * w0.y + a.y * w1.y + a.z * w2.y + a.w * w3.y;
                    acc[r].z += a.x * w0.z + a.y * w1.z + a.z * w2.z + a.w * w3.z;
                    acc[r].w += a.x * w0.w + a.y * w1.w + a.z * w2.w + a.w * w3.w;
                }
            }
        }
    }
#pragma unroll
    for (int r = 0; r < RPG; ++r) {
        long row = r0 + r;
        if (row < n) {
            float4 v = acc[r];
            v.x += bb.x; v.y += bb.y; v.z += bb.z; v.w += bb.w;
            float4 u = ((const float4*)du)[row * D4 + l];
            v.x = (u.x >= 0.1f) ? fmaxf(v.x, 0.f) * inv_keep : 0.f;
            v.y = (u.y >= 0.1f) ? fmaxf(v.y, 0.f) * inv_keep : 0.f;
            v.z = (u.z >= 0.1f) ? fmaxf(v.z, 0.f) * inv_keep : 0.f;
            v.w = (u.w >= 0.1f) ? fmaxf(v.w, 0.f) * inv_keep : 0.f;
            ((float4*)io)[row * D4 + l] = v;
        }
    }
}

extern "C" void kernel_launch(void* const* d_in, const int* in_sizes, int n_in,
                              void* d_out, int out_size, void* d_ws, size_t ws_size,
                              hipStream_t stream) {
    const float* x  = (const float*)d_in[0];
    const int*   ei = (const int*)d_in[1];    // [2,E] int32: row0=src, row1=dst
    const float* W  = (const float*)d_in[2];
    const float* b  = (const float*)d_in[3];
    const float* du = (const float*)d_in[4];
    float* out = (float*)d_out;

    const int n = in_sizes[0] / DIM;
    const int E = in_sizes[1] / 2;

    // workspace layout (256B-aligned slabs)
    auto al = [](size_t v) { return (v + 255) & ~(size_t)255; };
    char* ws = (char*)d_ws;
    size_t o_dinv = 0;
    size_t o_hist = o_dinv + al((size_t)n * 4);
    size_t o_rs   = o_hist + al((size_t)n * 4);
    size_t o_bsum = o_rs   + al(((size_t)n + 1) * 4);
    size_t o_src  = o_bsum + 1024;
    size_t o_xs   = o_src  + al((size_t)E * 4);
    size_t o_agg  = o_xs   + al((size_t)n * DIM * 2);
    size_t o_wt   = o_agg  + al((size_t)n * DIM * 2);
    size_t need1  = o_agg;                      // tier1: xs only
    size_t need2  = o_wt + (size_t)DIM * DIM * 2;

    float* dinv     = (float*)(ws + o_dinv);
    int*   hist     = (int*)(ws + o_hist);
    int*   rowstart = (int*)(ws + o_rs);
    int*   bsum     = (int*)(ws + o_bsum);
    int*   srclist  = (int*)(ws + o_src);
    unsigned* xs    = (unsigned*)(ws + o_xs);
    unsigned* agg   = (unsigned*)(ws + o_agg);
    unsigned short* wt = (unsigned short*)(ws + o_wt);

    const int bs = 256;
    const int B = (n + 1023) / 1024;

    hipMemsetAsync(hist, 0, (size_t)n * 4, stream);
    k_hist<<<(E + bs - 1) / bs, bs, 0, stream>>>(ei + E, E, hist);
    k_dinv<<<(n + bs - 1) / bs, bs, 0, stream>>>(hist, dinv, n);

    k_scan1<<<B, 256, 0, stream>>>(hist, rowstart, bsum, n);
    k_scan2<<<1, 256, 0, stream>>>(bsum, B);
    k_scan3<<<(n + 1 + bs - 1) / bs, bs, 0, stream>>>(rowstart, bsum, n, E);

    hipMemsetAsync(hist, 0, (size_t)n * 4, stream);   // hist reused as cursor
    k_fill<<<(E + bs - 1) / bs, bs, 0, stream>>>(ei, E, rowstart, hist, srclist);

    if (ws_size >= need2) {
        long t_x = (long)n * D4;
        k_xprep<<<(int)((t_x + bs - 1) / bs), bs, 0, stream>>>(x, dinv, xs, n);
        k_wprep<<<(DIM * DIM + bs - 1) / bs, bs, 0, stream>>>(W, wt);
        k_gather_bb<<<(n + 3) / 4, 256, 0, stream>>>(rowstart, srclist, xs, dinv, agg, n);
        int ntiles = (n + 31) / 32;
        int grid = ntiles < 1024 ? ntiles : 1024;
        k_mfma_transform<<<grid, 256, 0, stream>>>((const unsigned short*)agg, wt,
                                                   b, du, out, n, ntiles);
    } else if (ws_size >= need1) {
        long t_x = (long)n * D4;
        k_xprep<<<(int)((t_x + bs - 1) / bs), bs, 0, stream>>>(x, dinv, xs, n);
        k_gather_bf<<<(n + 3) / 4, 256, 0, stream>>>(rowstart, srclist, xs, dinv, out, n);
        int blocks_t = (int)((n + 63) / 64);
        k_transform<<<blocks_t, 256, 0, stream>>>(out, W, b, du, n);
    }
}

// Round 6
// 175.918 us; speedup vs baseline: 16.8733x; 1.6131x over previous
//
#include <hip/hip_runtime.h>

#define DIM 128
#define D4 32    // DIM/4
#define D2 64    // DIM/2
#define EPB1 4096   // edges per pass-1 block (8 iters x 512 threads)

typedef short short8 __attribute__((ext_vector_type(8)));   // 8 bf16 in 4 VGPRs
typedef float f32x4 __attribute__((ext_vector_type(4)));

// ---------- bf16 helpers (RNE) ----------
__device__ __forceinline__ unsigned pack_bf16(float a, float b) {
    unsigned ua = __float_as_uint(a);
    unsigned ub = __float_as_uint(b);
    ua = (ua + 0x7FFFu + ((ua >> 16) & 1u)) >> 16;        // RNE
    ub = (ub + 0x7FFFu + ((ub >> 16) & 1u)) & 0xFFFF0000u;
    return ua | ub;   // lo = a, hi = b
}
__device__ __forceinline__ unsigned short bf16_of(float a) {
    unsigned ua = __float_as_uint(a);
    return (unsigned short)((ua + 0x7FFFu + ((ua >> 16) & 1u)) >> 16);
}

// ================= tier-3: bucketed counting sort (no global-atomic scatter) ==========

// pass 1a: per-block LDS histogram of coarse bucket (dst>>9); H[bin*NB1+blk]; tot[bin]
__global__ __launch_bounds__(512) void k_hist1(const int* __restrict__ dst, int E,
                                               int* __restrict__ H, int* __restrict__ tot,
                                               int NB1, int NBUCK) {
    __shared__ int h[512];
    const int t = threadIdx.x;
    for (int i = t; i < NBUCK; i += 512) h[i] = 0;
    __syncthreads();
    const int base = blockIdx.x * EPB1;
#pragma unroll
    for (int i = 0; i < EPB1 / 512; ++i) {
        int e = base + i * 512 + t;
        if (e < E) atomicAdd(&h[dst[e] >> 9], 1);
    }
    __syncthreads();
    for (int i = t; i < NBUCK; i += 512) {
        int c = h[i];
        H[i * NB1 + blockIdx.x] = c;
        if (c) atomicAdd(&tot[i], c);
    }
}

// pass 1b: exclusive scan of bucket totals -> binbase[0..NBUCK]
__global__ __launch_bounds__(512) void k_scanA(const int* __restrict__ tot,
                                               int* __restrict__ binbase, int NBUCK) {
    __shared__ int sh[512];
    const int t = threadIdx.x;
    int v = (t < NBUCK) ? tot[t] : 0;
    sh[t] = v;
    __syncthreads();
    for (int o = 1; o < 512; o <<= 1) {
        int x = (t >= o) ? sh[t - o] : 0;
        __syncthreads();
        sh[t] += x;
        __syncthreads();
    }
    if (t < NBUCK) binbase[t] = sh[t] - v;
    if (t == NBUCK - 1) binbase[NBUCK] = sh[t];
}

// pass 1c: per-bin exclusive scan over blocks; H becomes global start of (bin,blk) run
__global__ __launch_bounds__(512) void k_scanB(int* __restrict__ H,
                                               const int* __restrict__ binbase, int NB1) {
    __shared__ int sh[512];
    const int bin = blockIdx.x;
    const int t = threadIdx.x;
    int v = (t < NB1) ? H[bin * NB1 + t] : 0;
    sh[t] = v;
    __syncthreads();
    for (int o = 1; o < 512; o <<= 1) {
        int x = (t >= o) ? sh[t - o] : 0;
        __syncthreads();
        sh[t] += x;
        __syncthreads();
    }
    if (t < NB1) H[bin * NB1 + t] = binbase[bin] + sh[t] - v;
}

// pass 1d: scatter packed (src<<9 | dstLo) into per-(bin,blk) runs (block-owned regions)
__global__ __launch_bounds__(512) void k_scatter1(const int* __restrict__ ei, int E,
                                                  const int* __restrict__ H,
                                                  unsigned* __restrict__ ebuf,
                                                  int NB1, int NBUCK) {
    __shared__ int cnt[512];
    const int t = threadIdx.x;
    const int blk = blockIdx.x;
    for (int i = t; i < NBUCK; i += 512) cnt[i] = 0;
    __syncthreads();
    const int* src = ei;
    const int* dst = ei + E;
    const int base = blk * EPB1;
#pragma unroll
    for (int i = 0; i < EPB1 / 512; ++i) {
        int e = base + i * 512 + t;
        if (e < E) {
            int d = dst[e];
            int s = src[e];
            int b = d >> 9;
            int r = atomicAdd(&cnt[b], 1);
            ebuf[H[b * NB1 + blk] + r] = ((unsigned)s << 9) | (unsigned)(d & 511);
        }
    }
}

// pass 2: one block per bucket: per-node hist (-> dinv, rowstart) + local scatter of srclist
__global__ __launch_bounds__(512) void k_bucket2(const unsigned* __restrict__ ebuf,
                                                 const int* __restrict__ binbase,
                                                 int* __restrict__ srclist,
                                                 int* __restrict__ rowstart,
                                                 float* __restrict__ dinv,
                                                 int n, int E) {
    __shared__ int h[512];
    __shared__ int off[512];
    __shared__ int cnt[512];
    const int t = threadIdx.x;
    const int b = blockIdx.x;
    const int beg = binbase[b];
    const int end = binbase[b + 1];
    h[t] = 0; cnt[t] = 0;
    __syncthreads();
    for (int j = beg + t; j < end; j += 512) atomicAdd(&h[ebuf[j] & 511], 1);
    __syncthreads();
    int v = h[t];
    off[t] = v;
    __syncthreads();
    for (int o = 1; o < 512; o <<= 1) {
        int x = (t >= o) ? off[t - o] : 0;
        __syncthreads();
        off[t] += x;
        __syncthreads();
    }
    const int excl = off[t] - v;
    const int node = b * 512 + t;
    if (node < n) {
        rowstart[node] = beg + excl;
        dinv[node] = rsqrtf((float)(v + 1));   // +1 self-loop
    }
    if (b == 0 && t == 0) rowstart[n] = E;
    h[t] = beg + excl;   // start position per lo-bin
    __syncthreads();
    for (int j = beg + t; j < end; j += 512) {
        unsigned p = ebuf[j];
        int lo = p & 511;
        int r = atomicAdd(&cnt[lo], 1);
        srclist[h[lo] + r] = (int)(p >> 9);
    }
}

// ================= shared tail kernels =================

// xs[i] = bf16(dinv[i] * x[i])  (pre-scaled gather payload)
__global__ __launch_bounds__(256) void k_xprep(const float* __restrict__ x,
                                               const float* __restrict__ dinv,
                                               unsigned* __restrict__ xs, int n) {
    long t = (long)blockIdx.x * blockDim.x + threadIdx.x;   // one per float4
    long total = (long)n * D4;
    if (t >= total) return;
    int row = (int)(t >> 5);
    float di = dinv[row];
    float4 v = ((const float4*)x)[t];
    uint2 o;
    o.x = pack_bf16(v.x * di, v.y * di);
    o.y = pack_bf16(v.z * di, v.w * di);
    ((uint2*)xs)[t] = o;
}

// W^T in bf16: wt[j*128 + k] = bf16(W[k*128 + j])
__global__ __launch_bounds__(256) void k_wprep(const float* __restrict__ W,
                                               unsigned short* __restrict__ wt) {
    int o = blockIdx.x * blockDim.x + threadIdx.x;
    if (o >= DIM * DIM) return;
    int j = o >> 7, k = o & 127;
    wt[o] = bf16_of(W[k * DIM + j]);
}

// pull aggregation, bf16 in / bf16 out (to ws)
__global__ __launch_bounds__(256) void k_gather_bb(const int* __restrict__ rowstart,
                                                   const int* __restrict__ srclist,
                                                   const unsigned* __restrict__ xs,
                                                   const float* __restrict__ dinv,
                                                   unsigned* __restrict__ agg, int n) {
    const int node = blockIdx.x * 4 + (threadIdx.x >> 6);
    const int lane = threadIdx.x & 63;
    if (node >= n) return;
    const float di = dinv[node];

    unsigned sv = xs[(long)node * D2 + lane];   // self-loop (has one dinv factor)
    float2 acc;
    acc.x = __uint_as_float(sv << 16);
    acc.y = __uint_as_float(sv & 0xFFFF0000u);

    const int beg = rowstart[node];
    const int end = rowstart[node + 1];
    int j = beg;
    for (; j + 3 < end; j += 4) {
        int s0 = srclist[j];
        int s1 = srclist[j + 1];
        int s2 = srclist[j + 2];
        int s3 = srclist[j + 3];
        unsigned v0 = xs[(long)s0 * D2 + lane];
        unsigned v1 = xs[(long)s1 * D2 + lane];
        unsigned v2 = xs[(long)s2 * D2 + lane];
        unsigned v3 = xs[(long)s3 * D2 + lane];
        acc.x += __uint_as_float(v0 << 16) + __uint_as_float(v1 << 16)
               + __uint_as_float(v2 << 16) + __uint_as_float(v3 << 16);
        acc.y += __uint_as_float(v0 & 0xFFFF0000u) + __uint_as_float(v1 & 0xFFFF0000u)
               + __uint_as_float(v2 & 0xFFFF0000u) + __uint_as_float(v3 & 0xFFFF0000u);
    }
    for (; j < end; ++j) {
        unsigned v0 = xs[(long)srclist[j] * D2 + lane];
        acc.x += __uint_as_float(v0 << 16);
        acc.y += __uint_as_float(v0 & 0xFFFF0000u);
    }
    agg[(long)node * D2 + lane] = pack_bf16(acc.x * di, acc.y * di);
}

// MFMA transform: out = dropout(relu(A @ W + b)), A bf16, W^T bf16
__global__ __launch_bounds__(256) void k_mfma_transform(
        const unsigned short* __restrict__ A,    // bf16 [n][128]
        const unsigned short* __restrict__ WT,   // bf16 [128 cols][128 k]
        const float* __restrict__ bias,
        const float* __restrict__ du,
        float* __restrict__ out, int n, int ntiles) {
    const int wave  = threadIdx.x >> 6;
    const int lane  = threadIdx.x & 63;
    const int rhalf = wave >> 1;
    const int cg    = wave & 1;
    const int lr    = lane & 15;
    const int lk8   = (lane >> 4) * 8;

    short8 bfr[4][4];
    float  bcol[4];
#pragma unroll
    for (int ct = 0; ct < 4; ++ct) {
        int col = cg * 64 + ct * 16 + lr;
        bcol[ct] = bias[col];
#pragma unroll
        for (int ks = 0; ks < 4; ++ks)
            bfr[ct][ks] = *reinterpret_cast<const short8*>(WT + col * DIM + ks * 32 + lk8);
    }

    for (int t = blockIdx.x; t < ntiles; t += gridDim.x) {
        const long row0 = (long)t * 32 + rhalf * 16;
        long ar = row0 + lr; if (ar >= n) ar = n - 1;
        short8 afr[4];
#pragma unroll
        for (int ks = 0; ks < 4; ++ks)
            afr[ks] = *reinterpret_cast<const short8*>(A + ar * DIM + ks * 32 + lk8);

#pragma unroll
        for (int ct = 0; ct < 4; ++ct) {
            f32x4 acc = {0.f, 0.f, 0.f, 0.f};
#pragma unroll
            for (int ks = 0; ks < 4; ++ks)
                acc = __builtin_amdgcn_mfma_f32_16x16x32_bf16(afr[ks], bfr[ct][ks], acc, 0, 0, 0);
            const int gcol = cg * 64 + ct * 16 + lr;
            const long rbase = row0 + (lane >> 4) * 4;
#pragma unroll
            for (int r = 0; r < 4; ++r) {
                long grow = rbase + r;
                if (grow < n) {
                    float v = acc[r] + bcol[ct];
                    float u = du[grow * DIM + gcol];
                    v = (u >= 0.1f) ? fmaxf(v, 0.f) * (1.0f / 0.9f) : 0.f;
                    out[grow * DIM + gcol] = v;
                }
            }
        }
    }
}

// ================= fallback tiers (atomic CSR build + VALU/MFMA) =================

__global__ void k_hist(const int* __restrict__ dst, int E, int* __restrict__ hist) {
    int e = blockIdx.x * blockDim.x + threadIdx.x;
    if (e < E) atomicAdd(&hist[dst[e]], 1);
}
__global__ void k_dinv(const int* __restrict__ hist, float* __restrict__ dinv, int n) {
    int i = blockIdx.x * blockDim.x + threadIdx.x;
    if (i < n) dinv[i] = rsqrtf((float)(hist[i] + 1));
}
__global__ __launch_bounds__(256) void k_scan1(const int* __restrict__ hist,
                                               int* __restrict__ rowstart,
                                               int* __restrict__ bsum, int n) {
    __shared__ int sh[256];
    const int t = threadIdx.x;
    const int base = blockIdx.x * 1024 + t * 4;
    int v0 = (base + 0 < n) ? hist[base + 0] : 0;
    int v1 = (base + 1 < n) ? hist[base + 1] : 0;
    int v2 = (base + 2 < n) ? hist[base + 2] : 0;
    int v3 = (base + 3 < n) ? hist[base + 3] : 0;
    int s = v0 + v1 + v2 + v3;
    sh[t] = s;
    __syncthreads();
    for (int off = 1; off < 256; off <<= 1) {
        int xv = (t >= off) ? sh[t - off] : 0;
        __syncthreads();
        sh[t] += xv;
        __syncthreads();
    }
    if (t == 255) bsum[blockIdx.x] = sh[255];
    int run = sh[t] - s;
    if (base + 0 < n) rowstart[base + 0] = run; run += v0;
    if (base + 1 < n) rowstart[base + 1] = run; run += v1;
    if (base + 2 < n) rowstart[base + 2] = run; run += v2;
    if (base + 3 < n) rowstart[base + 3] = run;
}
__global__ __launch_bounds__(256) void k_scan2(int* __restrict__ bsum, int B) {
    __shared__ int sh[256];
    const int t = threadIdx.x;
    int v = (t < B) ? bsum[t] : 0;
    sh[t] = v;
    __syncthreads();
    for (int off = 1; off < 256; off <<= 1) {
        int xv = (t >= off) ? sh[t - off] : 0;
        __syncthreads();
        sh[t] += xv;
        __syncthreads();
    }
    if (t < B) bsum[t] = sh[t] - v;
}
__global__ void k_scan3(int* __restrict__ rowstart, const int* __restrict__ bsum,
                        int n, int E) {
    int i = blockIdx.x * blockDim.x + threadIdx.x;
    if (i < n) rowstart[i] += bsum[i >> 10];
    else if (i == n) rowstart[n] = E;
}
__global__ void k_fill(const int* __restrict__ ei, int E,
                       const int* __restrict__ rowstart, int* __restrict__ cursor,
                       int* __restrict__ srclist) {
    int e = blockIdx.x * blockDim.x + threadIdx.x;
    if (e >= E) return;
    int d = ei[E + e];
    int pos = atomicAdd(&cursor[d], 1);
    srclist[rowstart[d] + pos] = ei[e];
}
__global__ __launch_bounds__(256) void k_gather_bf(const int* __restrict__ rowstart,
                                                   const int* __restrict__ srclist,
                                                   const unsigned* __restrict__ xs,
                                                   const float* __restrict__ dinv,
                                                   float* __restrict__ out, int n) {
    const int node = blockIdx.x * 4 + (threadIdx.x >> 6);
    const int lane = threadIdx.x & 63;
    if (node >= n) return;
    const float di = dinv[node];
    unsigned sv = xs[(long)node * D2 + lane];
    float2 acc;
    acc.x = __uint_as_float(sv << 16);
    acc.y = __uint_as_float(sv & 0xFFFF0000u);
    const int beg = rowstart[node];
    const int end = rowstart[node + 1];
    int j = beg;
    for (; j + 3 < end; j += 4) {
        int s0 = srclist[j]; int s1 = srclist[j + 1];
        int s2 = srclist[j + 2]; int s3 = srclist[j + 3];
        unsigned v0 = xs[(long)s0 * D2 + lane];
        unsigned v1 = xs[(long)s1 * D2 + lane];
        unsigned v2 = xs[(long)s2 * D2 + lane];
        unsigned v3 = xs[(long)s3 * D2 + lane];
        acc.x += __uint_as_float(v0 << 16) + __uint_as_float(v1 << 16)
               + __uint_as_float(v2 << 16) + __uint_as_float(v3 << 16);
        acc.y += __uint_as_float(v0 & 0xFFFF0000u) + __uint_as_float(v1 & 0xFFFF0000u)
               + __uint_as_float(v2 & 0xFFFF0000u) + __uint_as_float(v3 & 0xFFFF0000u);
    }
    for (; j < end; ++j) {
        unsigned v0 = xs[(long)srclist[j] * D2 + lane];
        acc.x += __uint_as_float(v0 << 16);
        acc.y += __uint_as_float(v0 & 0xFFFF0000u);
    }
    acc.x *= di; acc.y *= di;
    ((float2*)out)[(long)node * D2 + lane] = acc;
}
#define RPG 8
__global__ __launch_bounds__(256, 5) void k_transform(
        float* __restrict__ io, const float* __restrict__ W,
        const float* __restrict__ bias, const float* __restrict__ du, int n) {
    __shared__ float4 Wl[64 * D4];
    const float4* W4 = (const float4*)W;
    const int l = threadIdx.x & 31;
    const int g = threadIdx.x >> 5;
    const float4 bb = ((const float4*)bias)[l];
    const float inv_keep = 1.0f / 0.9f;
    long r0 = (long)blockIdx.x * 64 + (long)g * RPG;
    float4 acc[RPG];
#pragma unroll
    for (int r = 0; r < RPG; ++r) acc[r] = make_float4(0.f, 0.f, 0.f, 0.f);
    for (int half = 0; half < 2; ++half) {
        __syncthreads();
        for (int i = threadIdx.x; i < 64 * D4; i += 256)
            Wl[i] = W4[half * 64 * D4 + i];
        __syncthreads();
        const int kb = half * 16;
#pragma unroll 4
        for (int k4 = 0; k4 < 16; ++k4) {
            float4 w0 = Wl[(k4 * 4 + 0) * D4 + l];
            float4 w1 = Wl[(k4 * 4 + 1) * D4 + l];
            float4 w2 = Wl[(k4 * 4 + 2) * D4 + l];
            float4 w3 = Wl[(k4 * 4 + 3) * D4 + l];
#pragma unroll
            for (int r = 0; r < RPG; ++r) {
                long row = r0 + r;
                if (row < n) {
                    float4 a = ((const float4*)io)[row * D4 + kb + k4];
                    acc[r].x += a.x * w0.x + a.y * w1.x + a.z * w2.x + a.w * w3.x;
                    acc[r].y += a.x * w0.y + a.y * w1.y + a.z * w2.y + a.w * w3.y;
                    acc[r].z += a.x * w0.z + a.y * w1.z + a.z * w2.z + a.w * w3.z;
                    acc[r].w += a.x * w0.w + a.y * w1.w + a.z * w2.w + a.w * w3.w;
                }
            }
        }
    }
#pragma unroll
    for (int r = 0; r < RPG; ++r) {
        long row = r0 + r;
        if (row < n) {
            float4 v = acc[r];
            v.x += bb.x; v.y += bb.y; v.z += bb.z; v.w += bb.w;
            float4 u = ((const float4*)du)[row * D4 + l];
            v.x = (u.x >= 0.1f) ? fmaxf(v.x, 0.f) * inv_keep : 0.f;
            v.y = (u.y >= 0.1f) ? fmaxf(v.y, 0.f) * inv_keep : 0.f;
            v.z = (u.z >= 0.1f) ? fmaxf(v.z, 0.f) * inv_keep : 0.f;
            v.w = (u.w >= 0.1f) ? fmaxf(v.w, 0.f) * inv_keep : 0.f;
            ((float4*)io)[row * D4 + l] = v;
        }
    }
}

extern "C" void kernel_launch(void* const* d_in, const int* in_sizes, int n_in,
                              void* d_out, int out_size, void* d_ws, size_t ws_size,
                              hipStream_t stream) {
    const float* x  = (const float*)d_in[0];
    const int*   ei = (const int*)d_in[1];    // [2,E] int32: row0=src, row1=dst
    const float* W  = (const float*)d_in[2];
    const float* b  = (const float*)d_in[3];
    const float* du = (const float*)d_in[4];
    float* out = (float*)d_out;

    const int n = in_sizes[0] / DIM;
    const int E = in_sizes[1] / 2;

    auto al = [](size_t v) { return (v + 255) & ~(size_t)255; };
    char* ws = (char*)d_ws;

    const int NBUCK = (n + 511) >> 9;
    const int NB1   = (E + EPB1 - 1) / EPB1;

    // ---- tier-3 layout ----
    size_t o_dinv = 0;
    size_t o_rs   = o_dinv + al((size_t)n * 4);
    size_t o_src  = o_rs   + al(((size_t)n + 1) * 4);
    size_t o_xs   = o_src  + al((size_t)E * 4);
    size_t o_agg  = o_xs   + al((size_t)n * DIM * 2);
    size_t o_wt   = o_agg  + al((size_t)n * DIM * 2);
    size_t o_H    = o_wt   + al((size_t)DIM * DIM * 2);
    size_t o_tot  = o_H    + al((size_t)NBUCK * NB1 * 4);
    size_t o_bb   = o_tot  + al((size_t)NBUCK * 4);
    size_t o_ebuf = o_bb   + al(((size_t)NBUCK + 1) * 4);
    size_t need3  = o_ebuf + (size_t)E * 4;

    float* dinv     = (float*)(ws + o_dinv);
    int*   rowstart = (int*)(ws + o_rs);
    int*   srclist  = (int*)(ws + o_src);
    unsigned* xs    = (unsigned*)(ws + o_xs);
    unsigned* agg   = (unsigned*)(ws + o_agg);
    unsigned short* wt = (unsigned short*)(ws + o_wt);
    int*   H        = (int*)(ws + o_H);
    int*   tot      = (int*)(ws + o_tot);
    int*   binbase  = (int*)(ws + o_bb);
    unsigned* ebuf  = (unsigned*)(ws + o_ebuf);

    const int bs = 256;

    if (ws_size >= need3 && NBUCK <= 512 && NB1 <= 512) {
        // ---- bucketed counting sort: CSR + deg without global-atomic scatter ----
        hipMemsetAsync(tot, 0, (size_t)NBUCK * 4, stream);
        k_hist1<<<NB1, 512, 0, stream>>>(ei + E, E, H, tot, NB1, NBUCK);
        k_scanA<<<1, 512, 0, stream>>>(tot, binbase, NBUCK);
        k_scanB<<<NBUCK, 512, 0, stream>>>(H, binbase, NB1);
        k_scatter1<<<NB1, 512, 0, stream>>>(ei, E, H, ebuf, NB1, NBUCK);
        k_bucket2<<<NBUCK, 512, 0, stream>>>(ebuf, binbase, srclist, rowstart, dinv, n, E);

        long t_x = (long)n * D4;
        k_xprep<<<(int)((t_x + bs - 1) / bs), bs, 0, stream>>>(x, dinv, xs, n);
        k_wprep<<<(DIM * DIM + bs - 1) / bs, bs, 0, stream>>>(W, wt);
        k_gather_bb<<<(n + 3) / 4, 256, 0, stream>>>(rowstart, srclist, xs, dinv, agg, n);
        int ntiles = (n + 31) / 32;
        int grid = ntiles < 1024 ? ntiles : 1024;
        k_mfma_transform<<<grid, 256, 0, stream>>>((const unsigned short*)agg, wt,
                                                   b, du, out, n, ntiles);
        return;
    }

    // ---- fallback tiers: atomic CSR build ----
    size_t f_dinv = 0;
    size_t f_hist = f_dinv + al((size_t)n * 4);
    size_t f_rs   = f_hist + al((size_t)n * 4);
    size_t f_bsum = f_rs   + al(((size_t)n + 1) * 4);
    size_t f_src  = f_bsum + 1024;
    size_t f_xs   = f_src  + al((size_t)E * 4);
    size_t f_agg  = f_xs   + al((size_t)n * DIM * 2);
    size_t f_wt   = f_agg  + al((size_t)n * DIM * 2);
    size_t need1  = f_agg;
    size_t need2  = f_wt + (size_t)DIM * DIM * 2;

    float* fdinv     = (float*)(ws + f_dinv);
    int*   fhist     = (int*)(ws + f_hist);
    int*   frowstart = (int*)(ws + f_rs);
    int*   fbsum     = (int*)(ws + f_bsum);
    int*   fsrclist  = (int*)(ws + f_src);
    unsigned* fxs    = (unsigned*)(ws + f_xs);
    unsigned* fagg   = (unsigned*)(ws + f_agg);
    unsigned short* fwt = (unsigned short*)(ws + f_wt);

    const int B = (n + 1023) / 1024;
    hipMemsetAsync(fhist, 0, (size_t)n * 4, stream);
    k_hist<<<(E + bs - 1) / bs, bs, 0, stream>>>(ei + E, E, fhist);
    k_dinv<<<(n + bs - 1) / bs, bs, 0, stream>>>(fhist, fdinv, n);
    k_scan1<<<B, 256, 0, stream>>>(fhist, frowstart, fbsum, n);
    k_scan2<<<1, 256, 0, stream>>>(fbsum, B);
    k_scan3<<<(n + 1 + bs - 1) / bs, bs, 0, stream>>>(frowstart, fbsum, n, E);
    hipMemsetAsync(fhist, 0, (size_t)n * 4, stream);
    k_fill<<<(E + bs - 1) / bs, bs, 0, stream>>>(ei, E, frowstart, fhist, fsrclist);

    if (ws_size >= need2) {
        long t_x = (long)n * D4;
        k_xprep<<<(int)((t_x + bs - 1) / bs), bs, 0, stream>>>(x, fdinv, fxs, n);
        k_wprep<<<(DIM * DIM + bs - 1) / bs, bs, 0, stream>>>(W, fwt);
        k_gather_bb<<<(n + 3) / 4, 256, 0, stream>>>(frowstart, fsrclist, fxs, fdinv, fagg, n);
        int ntiles = (n + 31) / 32;
        int grid = ntiles < 1024 ? ntiles : 1024;
        k_mfma_transform<<<grid, 256, 0, stream>>>((const unsigned short*)fagg, fwt,
                                                   b, du, out, n, ntiles);
    } else if (ws_size >= need1) {
        long t_x = (long)n * D4;
        k_xprep<<<(int)((t_x + bs - 1) / bs), bs, 0, stream>>>(x, fdinv, fxs, n);
        k_gather_bf<<<(n + 3) / 4, 256, 0, stream>>>(frowstart, fsrclist, fxs, fdinv, out, n);
        int blocks_t = (int)((n + 63) / 64);
        k_transform<<<blocks_t, 256, 0, stream>>>(out, W, b, du, n);
    }
}

// Round 7
// 162.667 us; speedup vs baseline: 18.2478x; 1.0815x over previous
//
#include <hip/hip_runtime.h>

#define DIM 128
#define D4 32    // DIM/4
#define D2 64    // DIM/2
#define EPB1 4096   // edges per pass-1 block (8 iters x 512 threads)

typedef short short8 __attribute__((ext_vector_type(8)));   // 8 bf16 in 4 VGPRs
typedef float f32x4 __attribute__((ext_vector_type(4)));

// ---------- bf16 helpers (RNE) ----------
__device__ __forceinline__ unsigned pack_bf16(float a, float b) {
    unsigned ua = __float_as_uint(a);
    unsigned ub = __float_as_uint(b);
    ua = (ua + 0x7FFFu + ((ua >> 16) & 1u)) >> 16;        // RNE
    ub = (ub + 0x7FFFu + ((ub >> 16) & 1u)) & 0xFFFF0000u;
    return ua | ub;   // lo = a, hi = b
}
__device__ __forceinline__ unsigned short bf16_of(float a) {
    unsigned ua = __float_as_uint(a);
    return (unsigned short)((ua + 0x7FFFu + ((ua >> 16) & 1u)) >> 16);
}

// ================= tier-3: bucketed counting sort (no global-atomic scatter) ==========

// pass 1a: per-block LDS histogram of coarse bucket (dst>>9); H[bin*NB1+blk]; tot[bin]
// extra 8 trailing blocks convert W -> wt (bf16 W^T) to save a launch.
__global__ __launch_bounds__(512) void k_hist1(const int* __restrict__ dst, int E,
                                               int* __restrict__ H, int* __restrict__ tot,
                                               int NB1, int NBUCK,
                                               const float* __restrict__ W,
                                               unsigned short* __restrict__ wt) {
    if (blockIdx.x >= (unsigned)NB1) {
        // wprep part: 8 blocks x 512 threads x 4 elems = 16384
        int base = (blockIdx.x - NB1) * 2048 + threadIdx.x * 4;
#pragma unroll
        for (int i = 0; i < 4; ++i) {
            int o = base + i;
            if (o < DIM * DIM) {
                int j = o >> 7, k = o & 127;
                wt[o] = bf16_of(W[k * DIM + j]);
            }
        }
        return;
    }
    __shared__ int h[512];
    const int t = threadIdx.x;
    for (int i = t; i < NBUCK; i += 512) h[i] = 0;
    __syncthreads();
    const int base = blockIdx.x * EPB1;
#pragma unroll
    for (int i = 0; i < EPB1 / 512; ++i) {
        int e = base + i * 512 + t;
        if (e < E) atomicAdd(&h[dst[e] >> 9], 1);
    }
    __syncthreads();
    for (int i = t; i < NBUCK; i += 512) {
        int c = h[i];
        H[i * NB1 + blockIdx.x] = c;
        if (c) atomicAdd(&tot[i], c);
    }
}

// pass 1bc fused: block `bin` recomputes binbase locally from tot, scans its H row,
// and emits binbase[] for pass 2.
__global__ __launch_bounds__(512) void k_scanB(int* __restrict__ H,
                                               const int* __restrict__ tot,
                                               int* __restrict__ binbase,
                                               int NB1, int NBUCK, int E) {
    __shared__ int sh[512];
    const int bin = blockIdx.x;
    const int t = threadIdx.x;

    // scan of bucket totals (NBUCK <= 512)
    int tv = (t < NBUCK) ? tot[t] : 0;
    sh[t] = tv;
    __syncthreads();
    for (int o = 1; o < 512; o <<= 1) {
        int x = (t >= o) ? sh[t - o] : 0;
        __syncthreads();
        sh[t] += x;
        __syncthreads();
    }
    const int mybase = sh[bin] - ((bin < NBUCK) ? tot[bin] : 0);   // exclusive
    if (t == bin && t < NBUCK) binbase[t] = mybase;
    if (bin == 0 && t == 0) binbase[NBUCK] = E;
    __syncthreads();

    // scan this bin's H row over blocks
    int v = (t < NB1) ? H[bin * NB1 + t] : 0;
    sh[t] = v;
    __syncthreads();
    for (int o = 1; o < 512; o <<= 1) {
        int x = (t >= o) ? sh[t - o] : 0;
        __syncthreads();
        sh[t] += x;
        __syncthreads();
    }
    if (t < NB1) H[bin * NB1 + t] = mybase + sh[t] - v;
}

// pass 1d: scatter packed (src<<9 | dstLo) into per-(bin,blk) runs (block-owned regions)
__global__ __launch_bounds__(512) void k_scatter1(const int* __restrict__ ei, int E,
                                                  const int* __restrict__ H,
                                                  unsigned* __restrict__ ebuf,
                                                  int NB1, int NBUCK) {
    __shared__ int cnt[512];
    const int t = threadIdx.x;
    const int blk = blockIdx.x;
    for (int i = t; i < NBUCK; i += 512) cnt[i] = 0;
    __syncthreads();
    const int* src = ei;
    const int* dst = ei + E;
    const int base = blk * EPB1;
#pragma unroll
    for (int i = 0; i < EPB1 / 512; ++i) {
        int e = base + i * 512 + t;
        if (e < E) {
            int d = dst[e];
            int s = src[e];
            int b = d >> 9;
            int r = atomicAdd(&cnt[b], 1);
            ebuf[H[b * NB1 + blk] + r] = ((unsigned)s << 9) | (unsigned)(d & 511);
        }
    }
}

// pass 2: one block per bucket: per-node hist (-> dinv, rowstart) + local scatter of srclist
__global__ __launch_bounds__(512) void k_bucket2(const unsigned* __restrict__ ebuf,
                                                 const int* __restrict__ binbase,
                                                 int* __restrict__ srclist,
                                                 int* __restrict__ rowstart,
                                                 float* __restrict__ dinv,
                                                 int n, int E) {
    __shared__ int h[512];
    __shared__ int off[512];
    __shared__ int cnt[512];
    const int t = threadIdx.x;
    const int b = blockIdx.x;
    const int beg = binbase[b];
    const int end = binbase[b + 1];
    h[t] = 0; cnt[t] = 0;
    __syncthreads();
    for (int j = beg + t; j < end; j += 512) atomicAdd(&h[ebuf[j] & 511], 1);
    __syncthreads();
    int v = h[t];
    off[t] = v;
    __syncthreads();
    for (int o = 1; o < 512; o <<= 1) {
        int x = (t >= o) ? off[t - o] : 0;
        __syncthreads();
        off[t] += x;
        __syncthreads();
    }
    const int excl = off[t] - v;
    const int node = b * 512 + t;
    if (node < n) {
        rowstart[node] = beg + excl;
        dinv[node] = rsqrtf((float)(v + 1));   // +1 self-loop
    }
    if (b == 0 && t == 0) rowstart[n] = E;
    h[t] = beg + excl;   // start position per lo-bin
    __syncthreads();
    for (int j = beg + t; j < end; j += 512) {
        unsigned p = ebuf[j];
        int lo = p & 511;
        int r = atomicAdd(&cnt[lo], 1);
        srclist[h[lo] + r] = (int)(p >> 9);
    }
}

// ================= shared tail kernels =================

// xs[i] = bf16(dinv[i] * x[i])  (pre-scaled gather payload)
__global__ __launch_bounds__(256) void k_xprep(const float* __restrict__ x,
                                               const float* __restrict__ dinv,
                                               unsigned* __restrict__ xs, int n) {
    long t = (long)blockIdx.x * blockDim.x + threadIdx.x;   // one per float4
    long total = (long)n * D4;
    if (t >= total) return;
    int row = (int)(t >> 5);
    float di = dinv[row];
    float4 v = ((const float4*)x)[t];
    uint2 o;
    o.x = pack_bf16(v.x * di, v.y * di);
    o.y = pack_bf16(v.z * di, v.w * di);
    ((uint2*)xs)[t] = o;
}

// standalone W^T prep (fallback tiers)
__global__ __launch_bounds__(256) void k_wprep(const float* __restrict__ W,
                                               unsigned short* __restrict__ wt) {
    int o = blockIdx.x * blockDim.x + threadIdx.x;
    if (o >= DIM * DIM) return;
    int j = o >> 7, k = o & 127;
    wt[o] = bf16_of(W[k * DIM + j]);
}

// pull aggregation, bf16 in / bf16 out; srclist read once coalesced, broadcast via shfl
__global__ __launch_bounds__(256) void k_gather_bb(const int* __restrict__ rowstart,
                                                   const int* __restrict__ srclist,
                                                   const unsigned* __restrict__ xs,
                                                   const float* __restrict__ dinv,
                                                   unsigned* __restrict__ agg, int n) {
    const int node = blockIdx.x * 4 + (threadIdx.x >> 6);
    const int lane = threadIdx.x & 63;
    if (node >= n) return;
    const float di = dinv[node];

    unsigned sv = xs[(long)node * D2 + lane];   // self-loop (has one dinv factor)
    float ax = __uint_as_float(sv << 16);
    float ay = __uint_as_float(sv & 0xFFFF0000u);

    const int beg = rowstart[node];
    const int end = rowstart[node + 1];
    for (int base = beg; base < end; base += 64) {
        const int m = (end - base < 64) ? (end - base) : 64;
        int sidx = 0;
        if (base + lane < end) sidx = srclist[base + lane];
        int k = 0;
        for (; k + 3 < m; k += 4) {
            int s0 = __shfl(sidx, k);
            int s1 = __shfl(sidx, k + 1);
            int s2 = __shfl(sidx, k + 2);
            int s3 = __shfl(sidx, k + 3);
            unsigned v0 = xs[(long)s0 * D2 + lane];
            unsigned v1 = xs[(long)s1 * D2 + lane];
            unsigned v2 = xs[(long)s2 * D2 + lane];
            unsigned v3 = xs[(long)s3 * D2 + lane];
            ax += __uint_as_float(v0 << 16) + __uint_as_float(v1 << 16)
                + __uint_as_float(v2 << 16) + __uint_as_float(v3 << 16);
            ay += __uint_as_float(v0 & 0xFFFF0000u) + __uint_as_float(v1 & 0xFFFF0000u)
                + __uint_as_float(v2 & 0xFFFF0000u) + __uint_as_float(v3 & 0xFFFF0000u);
        }
        for (; k < m; ++k) {
            int s = __shfl(sidx, k);
            unsigned v = xs[(long)s * D2 + lane];
            ax += __uint_as_float(v << 16);
            ay += __uint_as_float(v & 0xFFFF0000u);
        }
    }
    agg[(long)node * D2 + lane] = pack_bf16(ax * di, ay * di);
}

// MFMA transform: out = dropout(relu(A @ W + b)), A bf16, W^T bf16
__global__ __launch_bounds__(256) void k_mfma_transform(
        const unsigned short* __restrict__ A,    // bf16 [n][128]
        const unsigned short* __restrict__ WT,   // bf16 [128 cols][128 k]
        const float* __restrict__ bias,
        const float* __restrict__ du,
        float* __restrict__ out, int n, int ntiles) {
    const int wave  = threadIdx.x >> 6;
    const int lane  = threadIdx.x & 63;
    const int rhalf = wave >> 1;
    const int cg    = wave & 1;
    const int lr    = lane & 15;
    const int lk8   = (lane >> 4) * 8;

    short8 bfr[4][4];
    float  bcol[4];
#pragma unroll
    for (int ct = 0; ct < 4; ++ct) {
        int col = cg * 64 + ct * 16 + lr;
        bcol[ct] = bias[col];
#pragma unroll
        for (int ks = 0; ks < 4; ++ks)
            bfr[ct][ks] = *reinterpret_cast<const short8*>(WT + col * DIM + ks * 32 + lk8);
    }

    for (int t = blockIdx.x; t < ntiles; t += gridDim.x) {
        const long row0 = (long)t * 32 + rhalf * 16;
        long ar = row0 + lr; if (ar >= n) ar = n - 1;
        short8 afr[4];
#pragma unroll
        for (int ks = 0; ks < 4; ++ks)
            afr[ks] = *reinterpret_cast<const short8*>(A + ar * DIM + ks * 32 + lk8);

#pragma unroll
        for (int ct = 0; ct < 4; ++ct) {
            f32x4 acc = {0.f, 0.f, 0.f, 0.f};
#pragma unroll
            for (int ks = 0; ks < 4; ++ks)
                acc = __builtin_amdgcn_mfma_f32_16x16x32_bf16(afr[ks], bfr[ct][ks], acc, 0, 0, 0);
            const int gcol = cg * 64 + ct * 16 + lr;
            const long rbase = row0 + (lane >> 4) * 4;
#pragma unroll
            for (int r = 0; r < 4; ++r) {
                long grow = rbase + r;
                if (grow < n) {
                    float v = acc[r] + bcol[ct];
                    float u = du[grow * DIM + gcol];
                    v = (u >= 0.1f) ? fmaxf(v, 0.f) * (1.0f / 0.9f) : 0.f;
                    out[grow * DIM + gcol] = v;
                }
            }
        }
    }
}

// ================= fallback tiers (atomic CSR build + VALU/MFMA) =================

__global__ void k_hist(const int* __restrict__ dst, int E, int* __restrict__ hist) {
    int e = blockIdx.x * blockDim.x + threadIdx.x;
    if (e < E) atomicAdd(&hist[dst[e]], 1);
}
__global__ void k_dinv(const int* __restrict__ hist, float* __restrict__ dinv, int n) {
    int i = blockIdx.x * blockDim.x + threadIdx.x;
    if (i < n) dinv[i] = rsqrtf((float)(hist[i] + 1));
}
__global__ __launch_bounds__(256) void k_scan1(const int* __restrict__ hist,
                                               int* __restrict__ rowstart,
                                               int* __restrict__ bsum, int n) {
    __shared__ int sh[256];
    const int t = threadIdx.x;
    const int base = blockIdx.x * 1024 + t * 4;
    int v0 = (base + 0 < n) ? hist[base + 0] : 0;
    int v1 = (base + 1 < n) ? hist[base + 1] : 0;
    int v2 = (base + 2 < n) ? hist[base + 2] : 0;
    int v3 = (base + 3 < n) ? hist[base + 3] : 0;
    int s = v0 + v1 + v2 + v3;
    sh[t] = s;
    __syncthreads();
    for (int off = 1; off < 256; off <<= 1) {
        int xv = (t >= off) ? sh[t - off] : 0;
        __syncthreads();
        sh[t] += xv;
        __syncthreads();
    }
    if (t == 255) bsum[blockIdx.x] = sh[255];
    int run = sh[t] - s;
    if (base + 0 < n) rowstart[base + 0] = run; run += v0;
    if (base + 1 < n) rowstart[base + 1] = run; run += v1;
    if (base + 2 < n) rowstart[base + 2] = run; run += v2;
    if (base + 3 < n) rowstart[base + 3] = run;
}
__global__ __launch_bounds__(256) void k_scan2(int* __restrict__ bsum, int B) {
    __shared__ int sh[256];
    const int t = threadIdx.x;
    int v = (t < B) ? bsum[t] : 0;
    sh[t] = v;
    __syncthreads();
    for (int off = 1; off < 256; off <<= 1) {
        int xv = (t >= off) ? sh[t - off] : 0;
        __syncthreads();
        sh[t] += xv;
        __syncthreads();
    }
    if (t < B) bsum[t] = sh[t] - v;
}
__global__ void k_scan3(int* __restrict__ rowstart, const int* __restrict__ bsum,
                        int n, int E) {
    int i = blockIdx.x * blockDim.x + threadIdx.x;
    if (i < n) rowstart[i] += bsum[i >> 10];
    else if (i == n) rowstart[n] = E;
}
__global__ void k_fill(const int* __restrict__ ei, int E,
                       const int* __restrict__ rowstart, int* __restrict__ cursor,
                       int* __restrict__ srclist) {
    int e = blockIdx.x * blockDim.x + threadIdx.x;
    if (e >= E) return;
    int d = ei[E + e];
    int pos = atomicAdd(&cursor[d], 1);
    srclist[rowstart[d] + pos] = ei[e];
}
__global__ __launch_bounds__(256) void k_gather_bf(const int* __restrict__ rowstart,
                                                   const int* __restrict__ srclist,
                                                   const unsigned* __restrict__ xs,
                                                   const float* __restrict__ dinv,
                                                   float* __restrict__ out, int n) {
    const int node = blockIdx.x * 4 + (threadIdx.x >> 6);
    const int lane = threadIdx.x & 63;
    if (node >= n) return;
    const float di = dinv[node];
    unsigned sv = xs[(long)node * D2 + lane];
    float2 acc;
    acc.x = __uint_as_float(sv << 16);
    acc.y = __uint_as_float(sv & 0xFFFF0000u);
    const int beg = rowstart[node];
    const int end = rowstart[node + 1];
    int j = beg;
    for (; j + 3 < end; j += 4) {
        int s0 = srclist[j]; int s1 = srclist[j + 1];
        int s2 = srclist[j + 2]; int s3 = srclist[j + 3];
        unsigned v0 = xs[(long)s0 * D2 + lane];
        unsigned v1 = xs[(long)s1 * D2 + lane];
        unsigned v2 = xs[(long)s2 * D2 + lane];
        unsigned v3 = xs[(long)s3 * D2 + lane];
        acc.x += __uint_as_float(v0 << 16) + __uint_as_float(v1 << 16)
               + __uint_as_float(v2 << 16) + __uint_as_float(v3 << 16);
        acc.y += __uint_as_float(v0 & 0xFFFF0000u) + __uint_as_float(v1 & 0xFFFF0000u)
               + __uint_as_float(v2 & 0xFFFF0000u) + __uint_as_float(v3 & 0xFFFF0000u);
    }
    for (; j < end; ++j) {
        unsigned v0 = xs[(long)srclist[j] * D2 + lane];
        acc.x += __uint_as_float(v0 << 16);
        acc.y += __uint_as_float(v0 & 0xFFFF0000u);
    }
    acc.x *= di; acc.y *= di;
    ((float2*)out)[(long)node * D2 + lane] = acc;
}
#define RPG 8
__global__ __launch_bounds__(256, 5) void k_transform(
        float* __restrict__ io, const float* __restrict__ W,
        const float* __restrict__ bias, const float* __restrict__ du, int n) {
    __shared__ float4 Wl[64 * D4];
    const float4* W4 = (const float4*)W;
    const int l = threadIdx.x & 31;
    const int g = threadIdx.x >> 5;
    const float4 bb = ((const float4*)bias)[l];
    const float inv_keep = 1.0f / 0.9f;
    long r0 = (long)blockIdx.x * 64 + (long)g * RPG;
    float4 acc[RPG];
#pragma unroll
    for (int r = 0; r < RPG; ++r) acc[r] = make_float4(0.f, 0.f, 0.f, 0.f);
    for (int half = 0; half < 2; ++half) {
        __syncthreads();
        for (int i = threadIdx.x; i < 64 * D4; i += 256)
            Wl[i] = W4[half * 64 * D4 + i];
        __syncthreads();
        const int kb = half * 16;
#pragma unroll 4
        for (int k4 = 0; k4 < 16; ++k4) {
            float4 w0 = Wl[(k4 * 4 + 0) * D4 + l];
            float4 w1 = Wl[(k4 * 4 + 1) * D4 + l];
            float4 w2 = Wl[(k4 * 4 + 2) * D4 + l];
            float4 w3 = Wl[(k4 * 4 + 3) * D4 + l];
#pragma unroll
            for (int r = 0; r < RPG; ++r) {
                long row = r0 + r;
                if (row < n) {
                    float4 a = ((const float4*)io)[row * D4 + kb + k4];
                    acc[r].x += a.x * w0.x + a.y * w1.x + a.z * w2.x + a.w * w3.x;
                    acc[r].y += a.x * w0.y + a.y * w1.y + a.z * w2.y + a.w * w3.y;
                    acc[r].z += a.x * w0.z + a.y * w1.z + a.z * w2.z + a.w * w3.z;
                    acc[r].w += a.x * w0.w + a.y * w1.w + a.z * w2.w + a.w * w3.w;
                }
            }
        }
    }
#pragma unroll
    for (int r = 0; r < RPG; ++r) {
        long row = r0 + r;
        if (row < n) {
            float4 v = acc[r];
            v.x += bb.x; v.y += bb.y; v.z += bb.z; v.w += bb.w;
            float4 u = ((const float4*)du)[row * D4 + l];
            v.x = (u.x >= 0.1f) ? fmaxf(v.x, 0.f) * inv_keep : 0.f;
            v.y = (u.y >= 0.1f) ? fmaxf(v.y, 0.f) * inv_keep : 0.f;
            v.z = (u.z >= 0.1f) ? fmaxf(v.z, 0.f) * inv_keep : 0.f;
            v.w = (u.w >= 0.1f) ? fmaxf(v.w, 0.f) * inv_keep : 0.f;
            ((float4*)io)[row * D4 + l] = v;
        }
    }
}

extern "C" void kernel_launch(void* const* d_in, const int* in_sizes, int n_in,
                              void* d_out, int out_size, void* d_ws, size_t ws_size,
                              hipStream_t stream) {
    const float* x  = (const float*)d_in[0];
    const int*   ei = (const int*)d_in[1];    // [2,E] int32: row0=src, row1=dst
    const float* W  = (const float*)d_in[2];
    const float* b  = (const float*)d_in[3];
    const float* du = (const float*)d_in[4];
    float* out = (float*)d_out;

    const int n = in_sizes[0] / DIM;
    const int E = in_sizes[1] / 2;

    auto al = [](size_t v) { return (v + 255) & ~(size_t)255; };
    char* ws = (char*)d_ws;

    const int NBUCK = (n + 511) >> 9;
    const int NB1   = (E + EPB1 - 1) / EPB1;

    // ---- tier-3 layout ----
    size_t o_dinv = 0;
    size_t o_rs   = o_dinv + al((size_t)n * 4);
    size_t o_src  = o_rs   + al(((size_t)n + 1) * 4);
    size_t o_xs   = o_src  + al((size_t)E * 4);
    size_t o_agg  = o_xs   + al((size_t)n * DIM * 2);
    size_t o_wt   = o_agg  + al((size_t)n * DIM * 2);
    size_t o_H    = o_wt   + al((size_t)DIM * DIM * 2);
    size_t o_tot  = o_H    + al((size_t)NBUCK * NB1 * 4);
    size_t o_bb   = o_tot  + al((size_t)NBUCK * 4);
    size_t o_ebuf = o_bb   + al(((size_t)NBUCK + 1) * 4);
    size_t need3  = o_ebuf + (size_t)E * 4;

    float* dinv     = (float*)(ws + o_dinv);
    int*   rowstart = (int*)(ws + o_rs);
    int*   srclist  = (int*)(ws + o_src);
    unsigned* xs    = (unsigned*)(ws + o_xs);
    unsigned* agg   = (unsigned*)(ws + o_agg);
    unsigned short* wt = (unsigned short*)(ws + o_wt);
    int*   H        = (int*)(ws + o_H);
    int*   tot      = (int*)(ws + o_tot);
    int*   binbase  = (int*)(ws + o_bb);
    unsigned* ebuf  = (unsigned*)(ws + o_ebuf);

    const int bs = 256;

    if (ws_size >= need3 && NBUCK <= 512 && NB1 <= 512) {
        // ---- bucketed counting sort: CSR + deg without global-atomic scatter ----
        hipMemsetAsync(tot, 0, (size_t)NBUCK * 4, stream);
        k_hist1<<<NB1 + 8, 512, 0, stream>>>(ei + E, E, H, tot, NB1, NBUCK, W, wt);
        k_scanB<<<NBUCK, 512, 0, stream>>>(H, tot, binbase, NB1, NBUCK, E);
        k_scatter1<<<NB1, 512, 0, stream>>>(ei, E, H, ebuf, NB1, NBUCK);
        k_bucket2<<<NBUCK, 512, 0, stream>>>(ebuf, binbase, srclist, rowstart, dinv, n, E);

        long t_x = (long)n * D4;
        k_xprep<<<(int)((t_x + bs - 1) / bs), bs, 0, stream>>>(x, dinv, xs, n);
        k_gather_bb<<<(n + 3) / 4, 256, 0, stream>>>(rowstart, srclist, xs, dinv, agg, n);
        int ntiles = (n + 31) / 32;
        int grid = ntiles < 1024 ? ntiles : 1024;
        k_mfma_transform<<<grid, 256, 0, stream>>>((const unsigned short*)agg, wt,
                                                   b, du, out, n, ntiles);
        return;
    }

    // ---- fallback tiers: atomic CSR build ----
    size_t f_dinv = 0;
    size_t f_hist = f_dinv + al((size_t)n * 4);
    size_t f_rs   = f_hist + al((size_t)n * 4);
    size_t f_bsum = f_rs   + al(((size_t)n + 1) * 4);
    size_t f_src  = f_bsum + 1024;
    size_t f_xs   = f_src  + al((size_t)E * 4);
    size_t f_agg  = f_xs   + al((size_t)n * DIM * 2);
    size_t f_wt   = f_agg  + al((size_t)n * DIM * 2);
    size_t need1  = f_agg;
    size_t need2  = f_wt + (size_t)DIM * DIM * 2;

    float* fdinv     = (float*)(ws + f_dinv);
    int*   fhist     = (int*)(ws + f_hist);
    int*   frowstart = (int*)(ws + f_rs);
    int*   fbsum     = (int*)(ws + f_bsum);
    int*   fsrclist  = (int*)(ws + f_src);
    unsigned* fxs    = (unsigned*)(ws + f_xs);
    unsigned* fagg   = (unsigned*)(ws + f_agg);
    unsigned short* fwt = (unsigned short*)(ws + f_wt);

    const int B = (n + 1023) / 1024;
    hipMemsetAsync(fhist, 0, (size_t)n * 4, stream);
    k_hist<<<(E + bs - 1) / bs, bs, 0, stream>>>(ei + E, E, fhist);
    k_dinv<<<(n + bs - 1) / bs, bs, 0, stream>>>(fhist, fdinv, n);
    k_scan1<<<B, 256, 0, stream>>>(fhist, frowstart, fbsum, n);
    k_scan2<<<1, 256, 0, stream>>>(fbsum, B);
    k_scan3<<<(n + 1 + bs - 1) / bs, bs, 0, stream>>>(frowstart, fbsum, n, E);
    hipMemsetAsync(fhist, 0, (size_t)n * 4, stream);
    k_fill<<<(E + bs - 1) / bs, bs, 0, stream>>>(ei, E, frowstart, fhist, fsrclist);

    if (ws_size >= need2) {
        long t_x = (long)n * D4;
        k_xprep<<<(int)((t_x + bs - 1) / bs), bs, 0, stream>>>(x, fdinv, fxs, n);
        k_wprep<<<(DIM * DIM + bs - 1) / bs, bs, 0, stream>>>(W, fwt);
        k_gather_bb<<<(n + 3) / 4, 256, 0, stream>>>(frowstart, fsrclist, fxs, fdinv, fagg, n);
        int ntiles = (n + 31) / 32;
        int grid = ntiles < 1024 ? ntiles : 1024;
        k_mfma_transform<<<grid, 256, 0, stream>>>((const unsigned short*)fagg, fwt,
                                                   b, du, out, n, ntiles);
    } else if (ws_size >= need1) {
        long t_x = (long)n * D4;
        k_xprep<<<(int)((t_x + bs - 1) / bs), bs, 0, stream>>>(x, fdinv, fxs, n);
        k_gather_bf<<<(n + 3) / 4, 256, 0, stream>>>(frowstart, fsrclist, fxs, fdinv, out, n);
        int blocks_t = (int)((n + 63) / 64);
        k_transform<<<blocks_t, 256, 0, stream>>>(out, W, b, du, n);
    }
}